// Round 9
// baseline (2931.709 us; speedup 1.0000x reference)
//
#include <hip/hip_runtime.h>

#define NN 200000
#define EE 800000
#define GG 2048
#define NBLK ((NN + 255) / 256)   // 782

typedef __attribute__((ext_vector_type(8))) short short8;
typedef __attribute__((ext_vector_type(4))) float f32x4;

__device__ __forceinline__ float bf2f(ushort u){
  unsigned x = ((unsigned)u) << 16;
  return __uint_as_float(x);
}
__device__ __forceinline__ ushort f2bf(float f){
  unsigned x = __float_as_uint(f);
  x += 0x7fffu + ((x >> 16) & 1u);
  return (ushort)(x >> 16);
}
__device__ __forceinline__ short8 pack8(float4 a, float4 b){
  short8 r;
  r[0]=(short)f2bf(a.x); r[1]=(short)f2bf(a.y); r[2]=(short)f2bf(a.z); r[3]=(short)f2bf(a.w);
  r[4]=(short)f2bf(b.x); r[5]=(short)f2bf(b.y); r[6]=(short)f2bf(b.z); r[7]=(short)f2bf(b.w);
  return r;
}

// swizzle a 256xK fp32 weight into MFMA B-fragment order (K=256)
__device__ __forceinline__ void swz256(const float* __restrict__ W, ushort* __restrict__ o, int idx){
  int ks = idx >> 13, rem = idx & 8191;
  int j16 = rem >> 9, rem2 = rem & 511;
  int ln = rem2 >> 3, t = rem2 & 7;
  int row = j16*16 + (ln & 15);
  int k = ks*32 + (ln >> 4)*8 + t;
  o[idx] = f2bf(W[(size_t)row*256 + k]);
}

// ---------------- prep: weight conversion/swizzle + edge-bias tables ----------------
__global__ __launch_bounds__(256) void prep_k(
    const float* __restrict__ W10, const float* __restrict__ W20,
    const float* __restrict__ W11, const float* __restrict__ W21,
    const float* __restrict__ W12, const float* __restrict__ W22,
    const float* __restrict__ lw0, const float* __restrict__ lb0,
    const float* __restrict__ lw1, const float* __restrict__ lb1,
    const float* __restrict__ lw2, const float* __restrict__ lb2,
    const float* __restrict__ eE, const float* __restrict__ mW1,
    const float* __restrict__ mW2,
    ushort* __restrict__ wb10, ushort* __restrict__ wb20,
    ushort* __restrict__ wb11, ushort* __restrict__ wb21,
    ushort* __restrict__ wb12, ushort* __restrict__ wb22,
    ushort* __restrict__ mW1b, ushort* __restrict__ mW2b,
    float* __restrict__ eb)
{
  int b = blockIdx.x, tid = threadIdx.x;
  if (b < 64){ // W1_0 (256x44) -> B-frag swizzled 256x64 (2 kslices), zero-padded
    int idx = b*256 + tid;
    int ks = idx >> 13, rem = idx & 8191;
    int j16 = rem >> 9, rem2 = rem & 511;
    int ln = rem2 >> 3, t = rem2 & 7;
    int row = j16*16 + (ln & 15);
    int k = ks*32 + (ln >> 4)*8 + t;
    wb10[idx] = (k < 44) ? f2bf(W10[row*44 + k]) : (ushort)0;
    return;
  }
  b -= 64;
  if (b < 256){ swz256(W20, wb20, b*256+tid); return; } b -= 256;
  if (b < 256){ swz256(W11, wb11, b*256+tid); return; } b -= 256;
  if (b < 256){ swz256(W21, wb21, b*256+tid); return; } b -= 256;
  if (b < 256){ swz256(W12, wb12, b*256+tid); return; } b -= 256;
  if (b < 256){ swz256(W22, wb22, b*256+tid); return; } b -= 256;
  if (b < 384){ // mW1 (256x323) -> padded row-major (256x384)
    int idx = b*256 + tid; int o = idx / 384, k = idx - o*384;
    mW1b[idx] = (k < 323) ? f2bf(mW1[(size_t)o*323 + k]) : (ushort)0;
    return;
  }
  b -= 384;
  if (b < 512){ int idx = b*256+tid; mW2b[idx] = f2bf(mW2[idx]); return; } b -= 512;
  int li = b >> 2, t = b & 3;
  const float* lw = (li == 0) ? lw0 : ((li == 1) ? lw1 : lw2);
  const float* lb = (li == 0) ? lb0 : ((li == 1) ? lb1 : lb2);
  int d = (li == 0) ? 44 : 256;
  float v = 0.f;
  if (tid < d){
    float a = 0.f;
    #pragma unroll
    for (int j = 0; j < 16; j++) a += eE[t*16 + j] * lw[tid*16 + j];
    v = a + lb[tid];
  }
  eb[(li*4 + t)*256 + tid] = v;
}

// ---------------- h0 = [op_embed[op], nums, 0-pad] as bf16 N x 64 ----------------
__global__ __launch_bounds__(256) void build_h0_k(
    const float* __restrict__ x, const float* __restrict__ opE, ushort* __restrict__ h0)
{
  int idx = blockIdx.x*256 + threadIdx.x;
  int i = idx >> 6, c = idx & 63;
  float v = 0.f;
  if (c < 32){
    int op = (int)x[(size_t)i*13];
    op = op < 0 ? 0 : (op > 63 ? 63 : op);
    v = opE[op*32 + c];
  } else if (c < 44){
    v = x[(size_t)i*13 + (c - 31)];
  }
  h0[idx] = f2bf(v);
}

// ================= CSR build =================
__global__ __launch_bounds__(256) void deg_k(const int* __restrict__ dst, int* __restrict__ D){
  int e = blockIdx.x*256 + threadIdx.x;
  atomicAdd(&D[dst[e]], 1);
}
__global__ __launch_bounds__(256) void scan1_k(int* __restrict__ D, int* __restrict__ bsum){
  __shared__ int s[256];
  int b = blockIdx.x, t = threadIdx.x, idx = b*256 + t;
  int v = (idx < NN) ? D[idx] : 0;
  s[t] = v; __syncthreads();
  for (int off = 1; off < 256; off <<= 1){
    int u = (t >= off) ? s[t-off] : 0;
    __syncthreads();
    s[t] += u;
    __syncthreads();
  }
  if (idx < NN) D[idx] = s[t] - v;
  if (t == 255) bsum[b] = s[255];
}
__global__ __launch_bounds__(256) void scan2_k(int* __restrict__ bsum){
  __shared__ int s[256];
  __shared__ int carry;
  int t = threadIdx.x;
  if (t == 0) carry = 0;
  __syncthreads();
  for (int c0 = 0; c0 < NBLK; c0 += 256){
    int idx = c0 + t;
    int v = (idx < NBLK) ? bsum[idx] : 0;
    s[t] = v; __syncthreads();
    for (int off = 1; off < 256; off <<= 1){
      int u = (t >= off) ? s[t-off] : 0;
      __syncthreads();
      s[t] += u;
      __syncthreads();
    }
    int ex = s[t] - v + carry;
    if (idx < NBLK) bsum[idx] = ex;
    int tot = s[255];
    __syncthreads();
    if (t == 0) carry += tot;
    __syncthreads();
  }
}
__global__ __launch_bounds__(256) void scan3_k(int* __restrict__ D, const int* __restrict__ bsum){
  int b = blockIdx.x, idx = b*256 + threadIdx.x;
  if (idx < NN) D[idx] += bsum[b];
}
// csr word: src (18b) | etype (2b @18) | local-row d&31 (5b @20)
__global__ __launch_bounds__(256) void fill_k(const int* __restrict__ src, const int* __restrict__ dst,
                                              const int* __restrict__ et, int* __restrict__ D,
                                              int* __restrict__ csr){
  int e = blockIdx.x*256 + threadIdx.x;
  int d = dst[e];
  int t = et[e]; t = t < 3 ? t : 3;
  int pos = atomicAdd(&D[d], 1);
  csr[pos] = src[e] | (t << 18) | ((d & 31) << 20);
}

// ---------------- fused layer: edge-parallel gather (LDS fp32 atomics) + MLP + LN ----------------
// 32 rows/block, grid 6250. Phase A: every edge is an independent loop iteration;
// z accumulates in fp32 AZ via conflict-free ds_add_f32 (col = lane + 64k).
template<int KD, int RESID>
__global__ __launch_bounds__(256) void layerf_k(
    const ushort* __restrict__ hsrc, const int* __restrict__ Dend, const int* __restrict__ csr,
    const float* __restrict__ ebL,
    const ushort* __restrict__ W1s, const float* __restrict__ b1,
    const ushort* __restrict__ W2s, const float* __restrict__ b2,
    const float* __restrict__ epsp, ushort* __restrict__ hout)
{
  __shared__ float AZ[32][264];                 // fp32 z-tile; later aliased as bf16 t-tile
  __shared__ float red1[32][4], red2[32][4], mnL[32], rsL[32];
  ushort* ZT = (ushort*)&AZ[0][0];              // [32][264] bf16 view (stride 264)
  const int tid = threadIdx.x, lane = tid & 63, wv = tid >> 6;
  const int l15 = lane & 15, lq = lane >> 4;
  const int rowBase = blockIdx.x * 32;
  const float epv = 1.0f + epsp[0];
  const int KV = (KD == 256) ? 4 : 1;           // col chunks per lane

  // edge-bias values for this lane's columns, all 4 etypes, in registers
  float ebv0[4], ebv1[4], ebv2[4], ebv3[4];
  #pragma unroll
  for (int k = 0; k < 4; k++){
    if (k < KV){
      ebv0[k] = ebL[0*256 + lane + 64*k];
      ebv1[k] = ebL[1*256 + lane + 64*k];
      ebv2[k] = ebL[2*256 + lane + 64*k];
      ebv3[k] = ebL[3*256 + lane + 64*k];
    } else { ebv0[k]=ebv1[k]=ebv2[k]=ebv3[k]=0.f; }
  }

  // ---- A0: init AZ = (1+eps) * h[row] ----
  #pragma unroll
  for (int it = 0; it < 8; it++){
    int rr = it*4 + wv;
    if (KD == 256){
      #pragma unroll
      for (int k = 0; k < 4; k++)
        AZ[rr][lane + 64*k] = epv * bf2f(hsrc[(size_t)(rowBase + rr)*256 + lane + 64*k]);
    } else {
      AZ[rr][lane] = epv * bf2f(hsrc[(size_t)(rowBase + rr)*64 + lane]);
    }
  }
  __syncthreads();

  // ---- A1: edge-parallel accumulate sum_e relu(h[src]+eb[et]) ----
  {
    int e0 = (rowBase == 0) ? 0 : Dend[rowBase - 1];
    int e1 = Dend[rowBase + 31];
    #pragma unroll 2
    for (int e = e0 + wv; e < e1; e += 4){
      int p = csr[e];
      int s = p & 0x3FFFF;
      int tt = (p >> 18) & 3;
      int lr = p >> 20;
      #pragma unroll
      for (int k = 0; k < KV; k++){
        float ee = (tt == 0) ? ebv0[k] : (tt == 1) ? ebv1[k] : (tt == 2) ? ebv2[k] : ebv3[k];
        float hv = bf2f(hsrc[(size_t)s*((KD==256)?256:64) + lane + 64*k]);
        float v = hv + ee;
        v = v > 0.f ? v : 0.f;
        atomicAdd(&AZ[lr][lane + 64*k], v);     // ds_add_f32, stride-1 -> conflict-free
      }
    }
  }
  __syncthreads();

  // ---- B: t = relu(z @ W1^T + b1), wave tile 32x64; A-frags from fp32 AZ ----
  f32x4 acc[2][4];
  #pragma unroll
  for (int i = 0; i < 2; i++)
    #pragma unroll
    for (int j = 0; j < 4; j++){ f32x4 z = {0.f,0.f,0.f,0.f}; acc[i][j] = z; }

  #pragma unroll
  for (int s = 0; s < KD/32; s++){
    short8 af[2], bfv[4];
    #pragma unroll
    for (int j = 0; j < 4; j++)
      bfv[j] = *(const short8*)(W1s + ((size_t)(s*16 + wv*4 + j)*64 + lane)*8);
    #pragma unroll
    for (int i = 0; i < 2; i++){
      const float4 f0 = *(const float4*)&AZ[i*16 + l15][s*32 + lq*8];
      const float4 f1 = *(const float4*)&AZ[i*16 + l15][s*32 + lq*8 + 4];
      af[i] = pack8(f0, f1);
    }
    #pragma unroll
    for (int i = 0; i < 2; i++)
      #pragma unroll
      for (int j = 0; j < 4; j++)
        acc[i][j] = __builtin_amdgcn_mfma_f32_16x16x32_bf16(af[i], bfv[j], acc[i][j], 0, 0, 0);
  }
  __syncthreads();   // all AZ reads complete; safe to overwrite as ZT

  // ---- C: t -> ZT (bf16 alias of AZ) ----
  {
    float b1c[4];
    #pragma unroll
    for (int j = 0; j < 4; j++) b1c[j] = b1[wv*64 + j*16 + l15];
    #pragma unroll
    for (int i = 0; i < 2; i++)
      #pragma unroll
      for (int j = 0; j < 4; j++){
        int cc = wv*64 + j*16 + l15;
        #pragma unroll
        for (int rg = 0; rg < 4; rg++){
          int r = i*16 + (lq << 2) + rg;
          float v = acc[i][j][rg] + b1c[j];
          v = v > 0.f ? v : 0.f;
          ZT[r*264 + cc] = f2bf(v);
        }
      }
  }
  __syncthreads();

  // ---- D: y = t @ W2^T ----
  #pragma unroll
  for (int i = 0; i < 2; i++)
    #pragma unroll
    for (int j = 0; j < 4; j++){ f32x4 z = {0.f,0.f,0.f,0.f}; acc[i][j] = z; }

  #pragma unroll
  for (int s = 0; s < 8; s++){
    short8 af[2], bfv[4];
    #pragma unroll
    for (int j = 0; j < 4; j++)
      bfv[j] = *(const short8*)(W2s + ((size_t)(s*16 + wv*4 + j)*64 + lane)*8);
    #pragma unroll
    for (int i = 0; i < 2; i++)
      af[i] = *(const short8*)&ZT[(i*16 + l15)*264 + s*32 + lq*8];
    #pragma unroll
    for (int i = 0; i < 2; i++)
      #pragma unroll
      for (int j = 0; j < 4; j++)
        acc[i][j] = __builtin_amdgcn_mfma_f32_16x16x32_bf16(af[i], bfv[j], acc[i][j], 0, 0, 0);
  }

  // ---- E: LayerNorm stats ----
  float b2c[4];
  #pragma unroll
  for (int j = 0; j < 4; j++) b2c[j] = b2[wv*64 + j*16 + l15];
  #pragma unroll
  for (int i = 0; i < 2; i++){
    #pragma unroll
    for (int rg = 0; rg < 4; rg++){
      float s1 = 0.f, s2 = 0.f;
      #pragma unroll
      for (int j = 0; j < 4; j++){
        float y = acc[i][j][rg] + b2c[j];
        s1 += y; s2 += y*y;
      }
      #pragma unroll
      for (int m = 1; m < 16; m <<= 1){
        s1 += __shfl_xor(s1, m, 64);
        s2 += __shfl_xor(s2, m, 64);
      }
      if (l15 == 0){
        int r = i*16 + (lq << 2) + rg;
        red1[r][wv] = s1; red2[r][wv] = s2;
      }
    }
  }
  __syncthreads();   // phase-D ZT reads complete
  if (tid < 32){
    float s1 = red1[tid][0] + red1[tid][1] + red1[tid][2] + red1[tid][3];
    float s2 = red2[tid][0] + red2[tid][1] + red2[tid][2] + red2[tid][3];
    float mn = s1 * (1.f/256.f);
    float vr = s2 * (1.f/256.f) - mn*mn;
    mnL[tid] = mn;
    rsL[tid] = rsqrtf(vr + 1e-5f);
  }
  __syncthreads();
  // ---- F: LN + resid (global re-read, L3-hot) + leaky -> ZT ----
  #pragma unroll
  for (int i = 0; i < 2; i++){
    #pragma unroll
    for (int rg = 0; rg < 4; rg++){
      int r = i*16 + (lq << 2) + rg;
      float mn = mnL[r], rs = rsL[r];
      #pragma unroll
      for (int j = 0; j < 4; j++){
        int cc = wv*64 + j*16 + l15;
        float y = acc[i][j][rg] + b2c[j];
        float v = (y - mn) * rs;
        if (RESID) v += bf2f(hsrc[(size_t)(rowBase + r)*256 + cc]);
        v = v > 0.f ? v : 0.1f*v;
        ZT[r*264 + cc] = f2bf(v);
      }
    }
  }
  __syncthreads();
  // ---- G: coalesced store ----
  #pragma unroll
  for (int p = 0; p < 8; p++){
    int r = p*4 + (tid >> 6);
    int c = (tid & 63) * 4;
    *(ushort4*)(hout + (size_t)(rowBase + r)*256 + c) = *(const ushort4*)&ZT[r*264 + c];
  }
}

// ---------------- readout -> catb bf16 (G x 384, zero-padded past 323) ----------------
__global__ __launch_bounds__(256) void readout_k(
    const ushort* __restrict__ h, const int* __restrict__ batch, const float* __restrict__ x,
    const int* __restrict__ sqlIds, const float* __restrict__ sqlMask,
    const float* __restrict__ tok, ushort* __restrict__ catb)
{
  int g = blockIdx.x, tid = threadIdx.x;
  __shared__ int se[2];
  __shared__ float part[4][64];
  __shared__ float mpart[4];
  if (tid < 2){
    int target = g + tid;
    int lo = 0, hi = NN;
    while (lo < hi){ int mid = (lo + hi) >> 1; if (batch[mid] < target) lo = mid + 1; else hi = mid; }
    se[tid] = lo;
  }
  __syncthreads();
  int start = se[0], end = se[1];
  float a = 0.f;
  for (int i = start; i < end; i++) a += bf2f(h[(size_t)i*256 + tid]);
  catb[(size_t)g*384 + tid] = f2bf(a);
  if (tid < 2){
    int col = (tid == 0) ? 5 : 4;
    float s = 0.f;
    for (int i = start; i < end; i++) s += x[(size_t)i*13 + col];
    float cnt = (float)(end - start);
    float dn = cnt > 1.f ? cnt : 1.f;
    if (tid == 0){ catb[(size_t)g*384 + 256] = f2bf(cnt); catb[(size_t)g*384 + 257] = f2bf(s / dn); }
    else { catb[(size_t)g*384 + 258] = f2bf(s / dn); }
  }
  int grp = tid >> 6, c = tid & 63;
  float acc = 0.f, m = 0.f;
  for (int s = grp; s < 128; s += 4){
    int id = sqlIds[g*128 + s];
    float mk = sqlMask[g*128 + s];
    m += mk;
    acc += tok[(size_t)id*64 + c] * mk;
  }
  part[grp][c] = acc;
  if (c == 0) mpart[grp] = m;
  __syncthreads();
  if (tid < 64){
    float L = mpart[0] + mpart[1] + mpart[2] + mpart[3];
    L = L > 1.f ? L : 1.f;
    float tsum = part[0][tid] + part[1][tid] + part[2][tid] + part[3][tid];
    catb[(size_t)g*384 + 259 + tid] = f2bf(tsum / L);
  }
  if (tid >= 64 && tid < 125){
    catb[(size_t)g*384 + 259 + tid] = 0;
  }
}

// ---------------- head GEMM1: hid = leaky(catb @ mW1b^T + mb1), bf16 out ----------------
__global__ __launch_bounds__(256) void head1_k(
    const ushort* __restrict__ catb, const ushort* __restrict__ W1b,
    const float* __restrict__ b1, ushort* __restrict__ hidb)
{
  __shared__ ushort smem[64*72 + 256*72];
  ushort (*As)[72] = (ushort(*)[72])smem;
  ushort (*Ws)[72] = (ushort(*)[72])(smem + 64*72);
  const int tid = threadIdx.x, lane = tid & 63, wv = tid >> 6;
  const int rowBase = blockIdx.x * 64;
  f32x4 acc[4][4];
  #pragma unroll
  for (int i = 0; i < 4; i++)
    #pragma unroll
    for (int j = 0; j < 4; j++){ f32x4 z = {0.f,0.f,0.f,0.f}; acc[i][j] = z; }

  for (int k0 = 0; k0 < 384; k0 += 64){
    __syncthreads();
    #pragma unroll
    for (int p = 0; p < 4; p++){
      int r = p*16 + (tid >> 4);
      int kk = (tid & 15) * 4;
      *(ushort4*)&As[r][kk] = *(const ushort4*)(catb + (size_t)(rowBase + r)*384 + k0 + kk);
    }
    #pragma unroll
    for (int p = 0; p < 16; p++){
      int oc = p*16 + (tid >> 4);
      int kk = (tid & 15) * 4;
      *(ushort4*)&Ws[oc][kk] = *(const ushort4*)(W1b + (size_t)oc*384 + k0 + kk);
    }
    __syncthreads();
    #pragma unroll
    for (int kc = 0; kc < 2; kc++){
      short8 af[4], bfv[4];
      #pragma unroll
      for (int i = 0; i < 4; i++)
        af[i] = *(const short8*)&As[i*16 + (lane & 15)][kc*32 + (lane >> 4)*8];
      #pragma unroll
      for (int j = 0; j < 4; j++)
        bfv[j] = *(const short8*)&Ws[wv*64 + j*16 + (lane & 15)][kc*32 + (lane >> 4)*8];
      #pragma unroll
      for (int i = 0; i < 4; i++)
        #pragma unroll
        for (int j = 0; j < 4; j++)
          acc[i][j] = __builtin_amdgcn_mfma_f32_16x16x32_bf16(af[i], bfv[j], acc[i][j], 0, 0, 0);
    }
  }
  __syncthreads();
  ushort (*Cs)[264] = (ushort(*)[264])smem;
  #pragma unroll
  for (int j = 0; j < 4; j++){
    int cc = wv*64 + j*16 + (lane & 15);
    float bb = b1[cc];
    #pragma unroll
    for (int i = 0; i < 4; i++){
      #pragma unroll
      for (int rg = 0; rg < 4; rg++){
        int r = i*16 + ((lane >> 4) << 2) + rg;
        float v = acc[i][j][rg] + bb;
        v = v > 0.f ? v : 0.1f*v;
        Cs[r][cc] = f2bf(v);
      }
    }
  }
  __syncthreads();
  #pragma unroll
  for (int p = 0; p < 16; p++){
    int r = p*4 + (tid >> 6);
    int c = (tid & 63) * 4;
    *(ushort4*)(hidb + (size_t)(rowBase + r)*256 + c) = *(const ushort4*)&Cs[r][c];
  }
}

// ---------------- head GEMM2: out = hidb @ mW2b^T + mb2, fp32 out ----------------
__global__ __launch_bounds__(256) void head2_k(
    const ushort* __restrict__ hidb, const ushort* __restrict__ W2b,
    const float* __restrict__ b2, float* __restrict__ out)
{
  __shared__ float smemf[128*132];
  ushort (*As)[72] = (ushort(*)[72])smemf;
  ushort (*Bs)[72] = (ushort(*)[72])((ushort*)smemf + 128*72);
  const int tid = threadIdx.x, lane = tid & 63, wv = tid >> 6;
  const int wr = (wv >> 1) * 64;
  const int wc = (wv & 1) * 64;
  const int rowBase = blockIdx.x * 128;
  const int colBase = blockIdx.y * 128;
  const int lr = tid >> 4, lk = (tid & 15) * 4;

  f32x4 acc[4][4];
  #pragma unroll
  for (int i = 0; i < 4; i++)
    #pragma unroll
    for (int j = 0; j < 4; j++){ f32x4 z = {0.f,0.f,0.f,0.f}; acc[i][j] = z; }

  for (int k0 = 0; k0 < 256; k0 += 64){
    __syncthreads();
    #pragma unroll
    for (int p = 0; p < 8; p++){
      int r = lr + p*16;
      *(ushort4*)&As[r][lk] = *(const ushort4*)(hidb + (size_t)(rowBase + r)*256 + k0 + lk);
      *(ushort4*)&Bs[r][lk] = *(const ushort4*)(W2b + (size_t)(colBase + r)*256 + k0 + lk);
    }
    __syncthreads();
    #pragma unroll
    for (int kc = 0; kc < 2; kc++){
      short8 af[4], bfv[4];
      #pragma unroll
      for (int i = 0; i < 4; i++)
        af[i] = *(const short8*)&As[wr + i*16 + (lane & 15)][kc*32 + (lane >> 4)*8];
      #pragma unroll
      for (int j = 0; j < 4; j++)
        bfv[j] = *(const short8*)&Bs[wc + j*16 + (lane & 15)][kc*32 + (lane >> 4)*8];
      #pragma unroll
      for (int i = 0; i < 4; i++)
        #pragma unroll
        for (int j = 0; j < 4; j++)
          acc[i][j] = __builtin_amdgcn_mfma_f32_16x16x32_bf16(af[i], bfv[j], acc[i][j], 0, 0, 0);
    }
  }
  __syncthreads();
  float (*Cs)[132] = (float(*)[132])smemf;
  #pragma unroll
  for (int j = 0; j < 4; j++){
    int cl = wc + j*16 + (lane & 15);
    float bb = b2[colBase + cl];
    #pragma unroll
    for (int i = 0; i < 4; i++){
      int r0 = wr + i*16 + ((lane >> 4) << 2);
      #pragma unroll
      for (int rg = 0; rg < 4; rg++)
        Cs[r0 + rg][cl] = acc[i][j][rg] + bb;
    }
  }
  __syncthreads();
  #pragma unroll
  for (int p = 0; p < 16; p++){
    int r = (tid >> 5) + p*8;
    int c4 = (tid & 31) * 4;
    *(float4*)(out + (size_t)(rowBase + r)*512 + colBase + c4) = *(const float4*)&Cs[r][c4];
  }
}

extern "C" void kernel_launch(void* const* d_in, const int* in_sizes, int n_in,
                              void* d_out, int out_size, void* d_ws, size_t ws_size,
                              hipStream_t stream)
{
  const float* x       = (const float*)d_in[0];
  const int*   ei      = (const int*)d_in[1];
  const int*   src     = ei;
  const int*   dst     = ei + EE;
  const int*   eattr   = (const int*)d_in[2];
  const int*   batch   = (const int*)d_in[3];
  const int*   sqlIds  = (const int*)d_in[4];
  const float* sqlMask = (const float*)d_in[5];
  const float* opE     = (const float*)d_in[6];
  const float* eE      = (const float*)d_in[7];
  const float* tok     = (const float*)d_in[8];
  const float* lw0 = (const float*)d_in[9],  *lb0 = (const float*)d_in[10], *eps0 = (const float*)d_in[11];
  const float* W10 = (const float*)d_in[12], *b10 = (const float*)d_in[13];
  const float* W20 = (const float*)d_in[14], *b20 = (const float*)d_in[15];
  const float* lw1 = (const float*)d_in[16], *lb1 = (const float*)d_in[17], *eps1 = (const float*)d_in[18];
  const float* W11 = (const float*)d_in[19], *b11 = (const float*)d_in[20];
  const float* W21 = (const float*)d_in[21], *b21 = (const float*)d_in[22];
  const float* lw2 = (const float*)d_in[23], *lb2 = (const float*)d_in[24], *eps2 = (const float*)d_in[25];
  const float* W12 = (const float*)d_in[26], *b12 = (const float*)d_in[27];
  const float* W22 = (const float*)d_in[28], *b22 = (const float*)d_in[29];
  const float* mW1 = (const float*)d_in[30], *mb1 = (const float*)d_in[31];
  const float* mW2 = (const float*)d_in[32], *mb2 = (const float*)d_in[33];
  float* out = (float*)d_out;

  // ---- workspace layout (same footprint as R8) ----
  char* ws = (char*)d_ws;
  size_t off = 0;
  const size_t NB256 = (size_t)NN*256*2;
  ushort* bufH    = (ushort*)(ws + off); off += NB256;   // h ping buffer
  char*   region  = ws + off;            off += NB256;   // h0 / h pong buffer / catb+hidb
  ushort* h0      = (ushort*)region;
  ushort* hPong   = (ushort*)region;
  ushort* catb    = (ushort*)region;
  ushort* hidb    = (ushort*)(region + (size_t)GG*384*2);
  ushort* wb10 = (ushort*)(ws + off); off += (size_t)256*64*2;
  ushort* wb20 = (ushort*)(ws + off); off += (size_t)65536*2;
  ushort* wb11 = (ushort*)(ws + off); off += (size_t)65536*2;
  ushort* wb21 = (ushort*)(ws + off); off += (size_t)65536*2;
  ushort* wb12 = (ushort*)(ws + off); off += (size_t)65536*2;
  ushort* wb22 = (ushort*)(ws + off); off += (size_t)65536*2;
  ushort* mW1b = (ushort*)(ws + off); off += (size_t)256*384*2;
  ushort* mW2b = (ushort*)(ws + off); off += (size_t)512*256*2;
  float*  eb   = (float*)(ws + off);  off += (size_t)3*4*256*4;
  int* D    = (int*)(ws + off); off += (size_t)NN*4;
  int* bsum = (int*)(ws + off); off += (size_t)NBLK*4;
  int* csr  = (int*)(ws + off); off += (size_t)EE*4;
  size_t needFast = off;

  if (ws_size < needFast) return;

  prep_k<<<2252, 256, 0, stream>>>(W10, W20, W11, W21, W12, W22,
                                   lw0, lb0, lw1, lb1, lw2, lb2, eE, mW1, mW2,
                                   wb10, wb20, wb11, wb21, wb12, wb22, mW1b, mW2b, eb);
  build_h0_k<<<50000, 256, 0, stream>>>(x, opE, h0);

  // ---- CSR build (by dst) ----
  hipMemsetAsync(D, 0, (size_t)NN*4, stream);
  deg_k<<<3125, 256, 0, stream>>>(dst, D);
  scan1_k<<<NBLK, 256, 0, stream>>>(D, bsum);
  scan2_k<<<1, 256, 0, stream>>>(bsum);
  scan3_k<<<NBLK, 256, 0, stream>>>(D, bsum);
  fill_k<<<3125, 256, 0, stream>>>(src, dst, eattr, D, csr); // D -> row ENDS

  // ---- fused layers (edge-parallel gather inside), ping-pong h ----
  layerf_k<64,0><<<6250, 256, 0, stream>>>(h0,    D, csr, eb,        wb10, b10, wb20, b20, eps0, bufH);
  layerf_k<256,1><<<6250, 256, 0, stream>>>(bufH, D, csr, eb + 1024, wb11, b11, wb21, b21, eps1, hPong);
  layerf_k<256,1><<<6250, 256, 0, stream>>>(hPong,D, csr, eb + 2048, wb12, b12, wb22, b22, eps2, bufH);

  // ---- readout + MFMA head ----
  readout_k<<<GG, 256, 0, stream>>>(bufH, batch, x, sqlIds, sqlMask, tok, catb);
  head1_k<<<32, 256, 0, stream>>>(catb, mW1b, mb1, hidb);
  head2_k<<<dim3(16, 4), 256, 0, stream>>>(hidb, mW2b, mb2, out);
}

// Round 10
// 884.107 us; speedup vs baseline: 3.3160x; 3.3160x over previous
//
#include <hip/hip_runtime.h>

#define NN 200000
#define EE 800000
#define GG 2048
#define NBLK ((NN + 255) / 256)   // 782

typedef __attribute__((ext_vector_type(8))) short short8;
typedef __attribute__((ext_vector_type(4))) float f32x4;

__device__ __forceinline__ float bf2f(ushort u){
  unsigned x = ((unsigned)u) << 16;
  return __uint_as_float(x);
}
__device__ __forceinline__ ushort f2bf(float f){
  unsigned x = __float_as_uint(f);
  x += 0x7fffu + ((x >> 16) & 1u);
  return (ushort)(x >> 16);
}

// swizzle a 256xK fp32 weight into MFMA B-fragment order (K=256)
__device__ __forceinline__ void swz256(const float* __restrict__ W, ushort* __restrict__ o, int idx){
  int ks = idx >> 13, rem = idx & 8191;
  int j16 = rem >> 9, rem2 = rem & 511;
  int ln = rem2 >> 3, t = rem2 & 7;
  int row = j16*16 + (ln & 15);
  int k = ks*32 + (ln >> 4)*8 + t;
  o[idx] = f2bf(W[(size_t)row*256 + k]);
}

// ---------------- prep: weight conversion/swizzle + edge-bias tables ----------------
__global__ __launch_bounds__(256) void prep_k(
    const float* __restrict__ W10, const float* __restrict__ W20,
    const float* __restrict__ W11, const float* __restrict__ W21,
    const float* __restrict__ W12, const float* __restrict__ W22,
    const float* __restrict__ lw0, const float* __restrict__ lb0,
    const float* __restrict__ lw1, const float* __restrict__ lb1,
    const float* __restrict__ lw2, const float* __restrict__ lb2,
    const float* __restrict__ eE, const float* __restrict__ mW1,
    const float* __restrict__ mW2,
    ushort* __restrict__ wb10, ushort* __restrict__ wb20,
    ushort* __restrict__ wb11, ushort* __restrict__ wb21,
    ushort* __restrict__ wb12, ushort* __restrict__ wb22,
    ushort* __restrict__ mW1b, ushort* __restrict__ mW2b,
    float* __restrict__ eb)
{
  int b = blockIdx.x, tid = threadIdx.x;
  if (b < 64){ // W1_0 (256x44) -> B-frag swizzled 256x64 (2 kslices), zero-padded
    int idx = b*256 + tid;
    int ks = idx >> 13, rem = idx & 8191;
    int j16 = rem >> 9, rem2 = rem & 511;
    int ln = rem2 >> 3, t = rem2 & 7;
    int row = j16*16 + (ln & 15);
    int k = ks*32 + (ln >> 4)*8 + t;
    wb10[idx] = (k < 44) ? f2bf(W10[row*44 + k]) : (ushort)0;
    return;
  }
  b -= 64;
  if (b < 256){ swz256(W20, wb20, b*256+tid); return; } b -= 256;
  if (b < 256){ swz256(W11, wb11, b*256+tid); return; } b -= 256;
  if (b < 256){ swz256(W21, wb21, b*256+tid); return; } b -= 256;
  if (b < 256){ swz256(W12, wb12, b*256+tid); return; } b -= 256;
  if (b < 256){ swz256(W22, wb22, b*256+tid); return; } b -= 256;
  if (b < 384){ // mW1 (256x323) -> padded row-major (256x384)
    int idx = b*256 + tid; int o = idx / 384, k = idx - o*384;
    mW1b[idx] = (k < 323) ? f2bf(mW1[(size_t)o*323 + k]) : (ushort)0;
    return;
  }
  b -= 384;
  if (b < 512){ int idx = b*256+tid; mW2b[idx] = f2bf(mW2[idx]); return; } b -= 512;
  int li = b >> 2, t = b & 3;
  const float* lw = (li == 0) ? lw0 : ((li == 1) ? lw1 : lw2);
  const float* lb = (li == 0) ? lb0 : ((li == 1) ? lb1 : lb2);
  int d = (li == 0) ? 44 : 256;
  float v = 0.f;
  if (tid < d){
    float a = 0.f;
    #pragma unroll
    for (int j = 0; j < 16; j++) a += eE[t*16 + j] * lw[tid*16 + j];
    v = a + lb[tid];
  }
  eb[(li*4 + t)*256 + tid] = v;
}

// ---------------- h0 = [op_embed[op], nums, 0-pad] as bf16 N x 64 ----------------
__global__ __launch_bounds__(256) void build_h0_k(
    const float* __restrict__ x, const float* __restrict__ opE, ushort* __restrict__ h0)
{
  int idx = blockIdx.x*256 + threadIdx.x;
  int i = idx >> 6, c = idx & 63;
  float v = 0.f;
  if (c < 32){
    int op = (int)x[(size_t)i*13];
    op = op < 0 ? 0 : (op > 63 ? 63 : op);
    v = opE[op*32 + c];
  } else if (c < 44){
    v = x[(size_t)i*13 + (c - 31)];
  }
  h0[idx] = f2bf(v);
}

// ================= CSR build =================
__global__ __launch_bounds__(256) void deg_k(const int* __restrict__ dst, int* __restrict__ D){
  int e = blockIdx.x*256 + threadIdx.x;
  atomicAdd(&D[dst[e]], 1);
}
__global__ __launch_bounds__(256) void scan1_k(int* __restrict__ D, int* __restrict__ bsum){
  __shared__ int s[256];
  int b = blockIdx.x, t = threadIdx.x, idx = b*256 + t;
  int v = (idx < NN) ? D[idx] : 0;
  s[t] = v; __syncthreads();
  for (int off = 1; off < 256; off <<= 1){
    int u = (t >= off) ? s[t-off] : 0;
    __syncthreads();
    s[t] += u;
    __syncthreads();
  }
  if (idx < NN) D[idx] = s[t] - v;
  if (t == 255) bsum[b] = s[255];
}
__global__ __launch_bounds__(256) void scan2_k(int* __restrict__ bsum){
  __shared__ int s[256];
  __shared__ int carry;
  int t = threadIdx.x;
  if (t == 0) carry = 0;
  __syncthreads();
  for (int c0 = 0; c0 < NBLK; c0 += 256){
    int idx = c0 + t;
    int v = (idx < NBLK) ? bsum[idx] : 0;
    s[t] = v; __syncthreads();
    for (int off = 1; off < 256; off <<= 1){
      int u = (t >= off) ? s[t-off] : 0;
      __syncthreads();
      s[t] += u;
      __syncthreads();
    }
    int ex = s[t] - v + carry;
    if (idx < NBLK) bsum[idx] = ex;
    int tot = s[255];
    __syncthreads();
    if (t == 0) carry += tot;
    __syncthreads();
  }
}
__global__ __launch_bounds__(256) void scan3_k(int* __restrict__ D, const int* __restrict__ bsum){
  int b = blockIdx.x, idx = b*256 + threadIdx.x;
  if (idx < NN) D[idx] += bsum[b];
}
__global__ __launch_bounds__(256) void fill_k(const int* __restrict__ src, const int* __restrict__ dst,
                                              const int* __restrict__ et, int* __restrict__ D,
                                              int* __restrict__ csr){
  int e = blockIdx.x*256 + threadIdx.x;
  int d = dst[e];
  int t = et[e]; t = t < 3 ? t : 3;
  int pos = atomicAdd(&D[d], 1);
  csr[pos] = src[e] | (t << 18);
}

// ---------------- fused layer: gather + z + GEMM1 + GEMM2 + LN + resid + leaky ----------------
// 32 rows/block, grid 6250. Phase A: QUAD-row edge streams per wave, float4 eb reads
// (ds_read_b128, conflict-free). Raw h stashed in HT for the residual.
template<int KD, int RESID>
__global__ __launch_bounds__(256) void layerf_k(
    const ushort* __restrict__ hsrc, const int* __restrict__ Dend, const int* __restrict__ csr,
    const float* __restrict__ ebL,
    const ushort* __restrict__ W1s, const float* __restrict__ b1,
    const ushort* __restrict__ W2s, const float* __restrict__ b2,
    const float* __restrict__ epsp, ushort* __restrict__ hout)
{
  __shared__ ushort ZT[32][264];
  __shared__ ushort HT[RESID ? 32 : 1][RESID ? 264 : 8];
  __shared__ float ebs[1024];
  __shared__ float red1[32][4], red2[32][4], mnL[32], rsL[32];
  const int tid = threadIdx.x, lane = tid & 63, wv = tid >> 6;
  const int l15 = lane & 15, lq = lane >> 4;
  const int rowBase = blockIdx.x * 32;
  const float epv = 1.0f + epsp[0];

  if (KD == 256){
    for (int i = tid; i < 1024; i += 256) ebs[i] = ebL[i];
  } else {
    if (tid < 256) ebs[tid] = ebL[(tid >> 6)*256 + (tid & 63)];  // compact [4][64]
  }
  __syncthreads();

  // ---- A: z = (1+eps)h[r] + sum_e relu(h[src]+eb[et]) -> ZT; raw h -> HT ----
  if (KD == 256){
    int c = lane * 4;
    #pragma unroll 1
    for (int it = 0; it < 2; it++){
      int rr0 = wv*8 + it*4;
      int r0 = rowBase + rr0;
      float4 A0, A1, A2, A3;
      {
        ushort4 q0 = *(const ushort4*)(hsrc + (size_t)(r0+0)*256 + c);
        ushort4 q1 = *(const ushort4*)(hsrc + (size_t)(r0+1)*256 + c);
        ushort4 q2 = *(const ushort4*)(hsrc + (size_t)(r0+2)*256 + c);
        ushort4 q3 = *(const ushort4*)(hsrc + (size_t)(r0+3)*256 + c);
        if (RESID){
          *(ushort4*)&HT[rr0+0][c] = q0;
          *(ushort4*)&HT[rr0+1][c] = q1;
          *(ushort4*)&HT[rr0+2][c] = q2;
          *(ushort4*)&HT[rr0+3][c] = q3;
        }
        A0 = make_float4(epv*bf2f(q0.x), epv*bf2f(q0.y), epv*bf2f(q0.z), epv*bf2f(q0.w));
        A1 = make_float4(epv*bf2f(q1.x), epv*bf2f(q1.y), epv*bf2f(q1.z), epv*bf2f(q1.w));
        A2 = make_float4(epv*bf2f(q2.x), epv*bf2f(q2.y), epv*bf2f(q2.z), epv*bf2f(q2.w));
        A3 = make_float4(epv*bf2f(q3.x), epv*bf2f(q3.y), epv*bf2f(q3.z), epv*bf2f(q3.w));
      }
      int bm1 = (r0 == 0) ? 0 : Dend[r0-1];
      int e0 = Dend[r0], e1 = Dend[r0+1], e2 = Dend[r0+2], e3 = Dend[r0+3];
      int st0 = bm1, st1 = e0, st2 = e1, st3 = e2;
      int n0 = e0 - st0, n1 = e1 - st1, n2 = e2 - st2, n3 = e3 - st3;
      int nmax = n0 > n1 ? n0 : n1;
      nmax = nmax > n2 ? nmax : n2;
      nmax = nmax > n3 ? nmax : n3;
      ushort4 z4; z4.x = z4.y = z4.z = z4.w = 0;
      ushort4 sv0 = z4, sv1 = z4, sv2 = z4, sv3 = z4;
      int t0 = 0, t1 = 0, t2 = 0, t3 = 0;
      if (n0 > 0){ int p = csr[st0]; sv0 = *(const ushort4*)(hsrc + (size_t)(p & 0x3FFFF)*256 + c); t0 = ((p >> 18) & 3)*256; }
      if (n1 > 0){ int p = csr[st1]; sv1 = *(const ushort4*)(hsrc + (size_t)(p & 0x3FFFF)*256 + c); t1 = ((p >> 18) & 3)*256; }
      if (n2 > 0){ int p = csr[st2]; sv2 = *(const ushort4*)(hsrc + (size_t)(p & 0x3FFFF)*256 + c); t2 = ((p >> 18) & 3)*256; }
      if (n3 > 0){ int p = csr[st3]; sv3 = *(const ushort4*)(hsrc + (size_t)(p & 0x3FFFF)*256 + c); t3 = ((p >> 18) & 3)*256; }
      for (int k = 0; k < nmax; k++){
        ushort4 c0 = sv0, c1 = sv1, c2 = sv2, c3 = sv3;
        int u0 = t0, u1 = t1, u2 = t2, u3 = t3;
        if (k+1 < n0){ int p = csr[st0+k+1]; sv0 = *(const ushort4*)(hsrc + (size_t)(p & 0x3FFFF)*256 + c); t0 = ((p >> 18) & 3)*256; }
        if (k+1 < n1){ int p = csr[st1+k+1]; sv1 = *(const ushort4*)(hsrc + (size_t)(p & 0x3FFFF)*256 + c); t1 = ((p >> 18) & 3)*256; }
        if (k+1 < n2){ int p = csr[st2+k+1]; sv2 = *(const ushort4*)(hsrc + (size_t)(p & 0x3FFFF)*256 + c); t2 = ((p >> 18) & 3)*256; }
        if (k+1 < n3){ int p = csr[st3+k+1]; sv3 = *(const ushort4*)(hsrc + (size_t)(p & 0x3FFFF)*256 + c); t3 = ((p >> 18) & 3)*256; }
        if (k < n0){
          const float4 ev = *(const float4*)&ebs[u0 + c];
          float v;
          v = bf2f(c0.x) + ev.x; A0.x += v > 0.f ? v : 0.f;
          v = bf2f(c0.y) + ev.y; A0.y += v > 0.f ? v : 0.f;
          v = bf2f(c0.z) + ev.z; A0.z += v > 0.f ? v : 0.f;
          v = bf2f(c0.w) + ev.w; A0.w += v > 0.f ? v : 0.f;
        }
        if (k < n1){
          const float4 ev = *(const float4*)&ebs[u1 + c];
          float v;
          v = bf2f(c1.x) + ev.x; A1.x += v > 0.f ? v : 0.f;
          v = bf2f(c1.y) + ev.y; A1.y += v > 0.f ? v : 0.f;
          v = bf2f(c1.z) + ev.z; A1.z += v > 0.f ? v : 0.f;
          v = bf2f(c1.w) + ev.w; A1.w += v > 0.f ? v : 0.f;
        }
        if (k < n2){
          const float4 ev = *(const float4*)&ebs[u2 + c];
          float v;
          v = bf2f(c2.x) + ev.x; A2.x += v > 0.f ? v : 0.f;
          v = bf2f(c2.y) + ev.y; A2.y += v > 0.f ? v : 0.f;
          v = bf2f(c2.z) + ev.z; A2.z += v > 0.f ? v : 0.f;
          v = bf2f(c2.w) + ev.w; A2.w += v > 0.f ? v : 0.f;
        }
        if (k < n3){
          const float4 ev = *(const float4*)&ebs[u3 + c];
          float v;
          v = bf2f(c3.x) + ev.x; A3.x += v > 0.f ? v : 0.f;
          v = bf2f(c3.y) + ev.y; A3.y += v > 0.f ? v : 0.f;
          v = bf2f(c3.z) + ev.z; A3.z += v > 0.f ? v : 0.f;
          v = bf2f(c3.w) + ev.w; A3.w += v > 0.f ? v : 0.f;
        }
      }
      ushort4 o;
      o.x = f2bf(A0.x); o.y = f2bf(A0.y); o.z = f2bf(A0.z); o.w = f2bf(A0.w);
      *(ushort4*)&ZT[rr0+0][c] = o;
      o.x = f2bf(A1.x); o.y = f2bf(A1.y); o.z = f2bf(A1.z); o.w = f2bf(A1.w);
      *(ushort4*)&ZT[rr0+1][c] = o;
      o.x = f2bf(A2.x); o.y = f2bf(A2.y); o.z = f2bf(A2.z); o.w = f2bf(A2.w);
      *(ushort4*)&ZT[rr0+2][c] = o;
      o.x = f2bf(A3.x); o.y = f2bf(A3.y); o.z = f2bf(A3.z); o.w = f2bf(A3.w);
      *(ushort4*)&ZT[rr0+3][c] = o;
    }
  } else {
    int c = l15 * 4;   // 16 lanes x 4 cols; 4 rows in parallel via lq
    #pragma unroll 1
    for (int it = 0; it < 2; it++){
      int rr = wv*8 + it*4 + lq;
      int r = rowBase + rr;
      const ushort4 hv = *(const ushort4*)(hsrc + (size_t)r*64 + c);
      float a0 = epv*bf2f(hv.x), a1 = epv*bf2f(hv.y), a2 = epv*bf2f(hv.z), a3 = epv*bf2f(hv.w);
      int st = (r == 0) ? 0 : Dend[r-1];
      int en = Dend[r];
      if (st < en){
        int p = csr[st];
        ushort4 sv = *(const ushort4*)(hsrc + (size_t)(p & 0x3FFFF)*64 + c);
        int tt = ((p >> 18) & 3)*64;
        for (int e = st; e < en; e++){
          ushort4 cur = sv; int tc = tt;
          int e2 = (e+1 < en) ? e+1 : e;
          int p2 = csr[e2];
          sv = *(const ushort4*)(hsrc + (size_t)(p2 & 0x3FFFF)*64 + c);
          tt = ((p2 >> 18) & 3)*64;
          const float4 ev = *(const float4*)&ebs[tc + c];
          float v;
          v = bf2f(cur.x) + ev.x; a0 += v > 0.f ? v : 0.f;
          v = bf2f(cur.y) + ev.y; a1 += v > 0.f ? v : 0.f;
          v = bf2f(cur.z) + ev.z; a2 += v > 0.f ? v : 0.f;
          v = bf2f(cur.w) + ev.w; a3 += v > 0.f ? v : 0.f;
        }
      }
      ushort4 o; o.x=f2bf(a0); o.y=f2bf(a1); o.z=f2bf(a2); o.w=f2bf(a3);
      *(ushort4*)&ZT[rr][c] = o;
    }
  }
  __syncthreads();

  // ---- B: t = relu(z @ W1^T + b1), wave tile 32x64 ----
  f32x4 acc[2][4];
  #pragma unroll
  for (int i = 0; i < 2; i++)
    #pragma unroll
    for (int j = 0; j < 4; j++){ f32x4 z = {0.f,0.f,0.f,0.f}; acc[i][j] = z; }

  #pragma unroll
  for (int s = 0; s < KD/32; s++){
    short8 af[2], bfv[4];
    #pragma unroll
    for (int j = 0; j < 4; j++)
      bfv[j] = *(const short8*)(W1s + ((size_t)(s*16 + wv*4 + j)*64 + lane)*8);
    #pragma unroll
    for (int i = 0; i < 2; i++)
      af[i] = *(const short8*)&ZT[i*16 + l15][s*32 + lq*8];
    #pragma unroll
    for (int i = 0; i < 2; i++)
      #pragma unroll
      for (int j = 0; j < 4; j++)
        acc[i][j] = __builtin_amdgcn_mfma_f32_16x16x32_bf16(af[i], bfv[j], acc[i][j], 0, 0, 0);
  }
  __syncthreads();

  // ---- C: t -> ZT ----
  {
    float b1c[4];
    #pragma unroll
    for (int j = 0; j < 4; j++) b1c[j] = b1[wv*64 + j*16 + l15];
    #pragma unroll
    for (int i = 0; i < 2; i++)
      #pragma unroll
      for (int j = 0; j < 4; j++){
        int cc = wv*64 + j*16 + l15;
        #pragma unroll
        for (int rg = 0; rg < 4; rg++){
          int r = i*16 + (lq << 2) + rg;
          float v = acc[i][j][rg] + b1c[j];
          v = v > 0.f ? v : 0.f;
          ZT[r][cc] = f2bf(v);
        }
      }
  }
  __syncthreads();

  // ---- D: y = t @ W2^T ----
  #pragma unroll
  for (int i = 0; i < 2; i++)
    #pragma unroll
    for (int j = 0; j < 4; j++){ f32x4 z = {0.f,0.f,0.f,0.f}; acc[i][j] = z; }

  #pragma unroll
  for (int s = 0; s < 8; s++){
    short8 af[2], bfv[4];
    #pragma unroll
    for (int j = 0; j < 4; j++)
      bfv[j] = *(const short8*)(W2s + ((size_t)(s*16 + wv*4 + j)*64 + lane)*8);
    #pragma unroll
    for (int i = 0; i < 2; i++)
      af[i] = *(const short8*)&ZT[i*16 + l15][s*32 + lq*8];
    #pragma unroll
    for (int i = 0; i < 2; i++)
      #pragma unroll
      for (int j = 0; j < 4; j++)
        acc[i][j] = __builtin_amdgcn_mfma_f32_16x16x32_bf16(af[i], bfv[j], acc[i][j], 0, 0, 0);
  }

  // ---- E: LayerNorm stats ----
  float b2c[4];
  #pragma unroll
  for (int j = 0; j < 4; j++) b2c[j] = b2[wv*64 + j*16 + l15];
  #pragma unroll
  for (int i = 0; i < 2; i++){
    #pragma unroll
    for (int rg = 0; rg < 4; rg++){
      float s1 = 0.f, s2 = 0.f;
      #pragma unroll
      for (int j = 0; j < 4; j++){
        float y = acc[i][j][rg] + b2c[j];
        s1 += y; s2 += y*y;
      }
      #pragma unroll
      for (int m = 1; m < 16; m <<= 1){
        s1 += __shfl_xor(s1, m, 64);
        s2 += __shfl_xor(s2, m, 64);
      }
      if (l15 == 0){
        int r = i*16 + (lq << 2) + rg;
        red1[r][wv] = s1; red2[r][wv] = s2;
      }
    }
  }
  __syncthreads();
  if (tid < 32){
    float s1 = red1[tid][0] + red1[tid][1] + red1[tid][2] + red1[tid][3];
    float s2 = red2[tid][0] + red2[tid][1] + red2[tid][2] + red2[tid][3];
    float mn = s1 * (1.f/256.f);
    float vr = s2 * (1.f/256.f) - mn*mn;
    mnL[tid] = mn;
    rsL[tid] = rsqrtf(vr + 1e-5f);
  }
  __syncthreads();
  // ---- F: LN + resid(HT) + leaky -> ZT ----
  #pragma unroll
  for (int i = 0; i < 2; i++){
    #pragma unroll
    for (int rg = 0; rg < 4; rg++){
      int r = i*16 + (lq << 2) + rg;
      float mn = mnL[r], rs = rsL[r];
      #pragma unroll
      for (int j = 0; j < 4; j++){
        int cc = wv*64 + j*16 + l15;
        float y = acc[i][j][rg] + b2c[j];
        float v = (y - mn) * rs;
        if (RESID) v += bf2f(HT[r][cc]);
        v = v > 0.f ? v : 0.1f*v;
        ZT[r][cc] = f2bf(v);
      }
    }
  }
  __syncthreads();
  // ---- G: coalesced store ----
  #pragma unroll
  for (int p = 0; p < 8; p++){
    int r = p*4 + (tid >> 6);
    int c = (tid & 63) * 4;
    *(ushort4*)(hout + (size_t)(rowBase + r)*256 + c) = *(const ushort4*)&ZT[r][c];
  }
}

// ---------------- readout -> catb bf16 (G x 384, zero-padded past 323) ----------------
__global__ __launch_bounds__(256) void readout_k(
    const ushort* __restrict__ h, const int* __restrict__ batch, const float* __restrict__ x,
    const int* __restrict__ sqlIds, const float* __restrict__ sqlMask,
    const float* __restrict__ tok, ushort* __restrict__ catb)
{
  int g = blockIdx.x, tid = threadIdx.x;
  __shared__ int se[2];
  __shared__ float part[4][64];
  __shared__ float mpart[4];
  if (tid < 2){
    int target = g + tid;
    int lo = 0, hi = NN;
    while (lo < hi){ int mid = (lo + hi) >> 1; if (batch[mid] < target) lo = mid + 1; else hi = mid; }
    se[tid] = lo;
  }
  __syncthreads();
  int start = se[0], end = se[1];
  float a = 0.f;
  for (int i = start; i < end; i++) a += bf2f(h[(size_t)i*256 + tid]);
  catb[(size_t)g*384 + tid] = f2bf(a);
  if (tid < 2){
    int col = (tid == 0) ? 5 : 4;
    float s = 0.f;
    for (int i = start; i < end; i++) s += x[(size_t)i*13 + col];
    float cnt = (float)(end - start);
    float dn = cnt > 1.f ? cnt : 1.f;
    if (tid == 0){ catb[(size_t)g*384 + 256] = f2bf(cnt); catb[(size_t)g*384 + 257] = f2bf(s / dn); }
    else { catb[(size_t)g*384 + 258] = f2bf(s / dn); }
  }
  int grp = tid >> 6, c = tid & 63;
  float acc = 0.f, m = 0.f;
  for (int s = grp; s < 128; s += 4){
    int id = sqlIds[g*128 + s];
    float mk = sqlMask[g*128 + s];
    m += mk;
    acc += tok[(size_t)id*64 + c] * mk;
  }
  part[grp][c] = acc;
  if (c == 0) mpart[grp] = m;
  __syncthreads();
  if (tid < 64){
    float L = mpart[0] + mpart[1] + mpart[2] + mpart[3];
    L = L > 1.f ? L : 1.f;
    float tsum = part[0][tid] + part[1][tid] + part[2][tid] + part[3][tid];
    catb[(size_t)g*384 + 259 + tid] = f2bf(tsum / L);
  }
  if (tid >= 64 && tid < 125){
    catb[(size_t)g*384 + 259 + tid] = 0;
  }
}

// ---------------- head GEMM1: hid = leaky(catb @ mW1b^T + mb1), bf16 out ----------------
__global__ __launch_bounds__(256) void head1_k(
    const ushort* __restrict__ catb, const ushort* __restrict__ W1b,
    const float* __restrict__ b1, ushort* __restrict__ hidb)
{
  __shared__ ushort smem[64*72 + 256*72];
  ushort (*As)[72] = (ushort(*)[72])smem;
  ushort (*Ws)[72] = (ushort(*)[72])(smem + 64*72);
  const int tid = threadIdx.x, lane = tid & 63, wv = tid >> 6;
  const int rowBase = blockIdx.x * 64;
  f32x4 acc[4][4];
  #pragma unroll
  for (int i = 0; i < 4; i++)
    #pragma unroll
    for (int j = 0; j < 4; j++){ f32x4 z = {0.f,0.f,0.f,0.f}; acc[i][j] = z; }

  for (int k0 = 0; k0 < 384; k0 += 64){
    __syncthreads();
    #pragma unroll
    for (int p = 0; p < 4; p++){
      int r = p*16 + (tid >> 4);
      int kk = (tid & 15) * 4;
      *(ushort4*)&As[r][kk] = *(const ushort4*)(catb + (size_t)(rowBase + r)*384 + k0 + kk);
    }
    #pragma unroll
    for (int p = 0; p < 16; p++){
      int oc = p*16 + (tid >> 4);
      int kk = (tid & 15) * 4;
      *(ushort4*)&Ws[oc][kk] = *(const ushort4*)(W1b + (size_t)oc*384 + k0 + kk);
    }
    __syncthreads();
    #pragma unroll
    for (int kc = 0; kc < 2; kc++){
      short8 af[4], bfv[4];
      #pragma unroll
      for (int i = 0; i < 4; i++)
        af[i] = *(const short8*)&As[i*16 + (lane & 15)][kc*32 + (lane >> 4)*8];
      #pragma unroll
      for (int j = 0; j < 4; j++)
        bfv[j] = *(const short8*)&Ws[wv*64 + j*16 + (lane & 15)][kc*32 + (lane >> 4)*8];
      #pragma unroll
      for (int i = 0; i < 4; i++)
        #pragma unroll
        for (int j = 0; j < 4; j++)
          acc[i][j] = __builtin_amdgcn_mfma_f32_16x16x32_bf16(af[i], bfv[j], acc[i][j], 0, 0, 0);
    }
  }
  __syncthreads();
  ushort (*Cs)[264] = (ushort(*)[264])smem;
  #pragma unroll
  for (int j = 0; j < 4; j++){
    int cc = wv*64 + j*16 + (lane & 15);
    float bb = b1[cc];
    #pragma unroll
    for (int i = 0; i < 4; i++){
      #pragma unroll
      for (int rg = 0; rg < 4; rg++){
        int r = i*16 + ((lane >> 4) << 2) + rg;
        float v = acc[i][j][rg] + bb;
        v = v > 0.f ? v : 0.1f*v;
        Cs[r][cc] = f2bf(v);
      }
    }
  }
  __syncthreads();
  #pragma unroll
  for (int p = 0; p < 16; p++){
    int r = p*4 + (tid >> 6);
    int c = (tid & 63) * 4;
    *(ushort4*)(hidb + (size_t)(rowBase + r)*256 + c) = *(const ushort4*)&Cs[r][c];
  }
}

// ---------------- head GEMM2: out = hidb @ mW2b^T + mb2, fp32 out ----------------
__global__ __launch_bounds__(256) void head2_k(
    const ushort* __restrict__ hidb, const ushort* __restrict__ W2b,
    const float* __restrict__ b2, float* __restrict__ out)
{
  __shared__ float smemf[128*132];
  ushort (*As)[72] = (ushort(*)[72])smemf;
  ushort (*Bs)[72] = (ushort(*)[72])((ushort*)smemf + 128*72);
  const int tid = threadIdx.x, lane = tid & 63, wv = tid >> 6;
  const int wr = (wv >> 1) * 64;
  const int wc = (wv & 1) * 64;
  const int rowBase = blockIdx.x * 128;
  const int colBase = blockIdx.y * 128;
  const int lr = tid >> 4, lk = (tid & 15) * 4;

  f32x4 acc[4][4];
  #pragma unroll
  for (int i = 0; i < 4; i++)
    #pragma unroll
    for (int j = 0; j < 4; j++){ f32x4 z = {0.f,0.f,0.f,0.f}; acc[i][j] = z; }

  for (int k0 = 0; k0 < 256; k0 += 64){
    __syncthreads();
    #pragma unroll
    for (int p = 0; p < 8; p++){
      int r = lr + p*16;
      *(ushort4*)&As[r][lk] = *(const ushort4*)(hidb + (size_t)(rowBase + r)*256 + k0 + lk);
      *(ushort4*)&Bs[r][lk] = *(const ushort4*)(W2b + (size_t)(colBase + r)*256 + k0 + lk);
    }
    __syncthreads();
    #pragma unroll
    for (int kc = 0; kc < 2; kc++){
      short8 af[4], bfv[4];
      #pragma unroll
      for (int i = 0; i < 4; i++)
        af[i] = *(const short8*)&As[wr + i*16 + (lane & 15)][kc*32 + (lane >> 4)*8];
      #pragma unroll
      for (int j = 0; j < 4; j++)
        bfv[j] = *(const short8*)&Bs[wc + j*16 + (lane & 15)][kc*32 + (lane >> 4)*8];
      #pragma unroll
      for (int i = 0; i < 4; i++)
        #pragma unroll
        for (int j = 0; j < 4; j++)
          acc[i][j] = __builtin_amdgcn_mfma_f32_16x16x32_bf16(af[i], bfv[j], acc[i][j], 0, 0, 0);
    }
  }
  __syncthreads();
  float (*Cs)[132] = (float(*)[132])smemf;
  #pragma unroll
  for (int j = 0; j < 4; j++){
    int cl = wc + j*16 + (lane & 15);
    float bb = b2[colBase + cl];
    #pragma unroll
    for (int i = 0; i < 4; i++){
      int r0 = wr + i*16 + ((lane >> 4) << 2);
      #pragma unroll
      for (int rg = 0; rg < 4; rg++)
        Cs[r0 + rg][cl] = acc[i][j][rg] + bb;
    }
  }
  __syncthreads();
  #pragma unroll
  for (int p = 0; p < 16; p++){
    int r = (tid >> 5) + p*8;
    int c4 = (tid & 31) * 4;
    *(float4*)(out + (size_t)(rowBase + r)*512 + colBase + c4) = *(const float4*)&Cs[r][c4];
  }
}

extern "C" void kernel_launch(void* const* d_in, const int* in_sizes, int n_in,
                              void* d_out, int out_size, void* d_ws, size_t ws_size,
                              hipStream_t stream)
{
  const float* x       = (const float*)d_in[0];
  const int*   ei      = (const int*)d_in[1];
  const int*   src     = ei;
  const int*   dst     = ei + EE;
  const int*   eattr   = (const int*)d_in[2];
  const int*   batch   = (const int*)d_in[3];
  const int*   sqlIds  = (const int*)d_in[4];
  const float* sqlMask = (const float*)d_in[5];
  const float* opE     = (const float*)d_in[6];
  const float* eE      = (const float*)d_in[7];
  const float* tok     = (const float*)d_in[8];
  const float* lw0 = (const float*)d_in[9],  *lb0 = (const float*)d_in[10], *eps0 = (const float*)d_in[11];
  const float* W10 = (const float*)d_in[12], *b10 = (const float*)d_in[13];
  const float* W20 = (const float*)d_in[14], *b20 = (const float*)d_in[15];
  const float* lw1 = (const float*)d_in[16], *lb1 = (const float*)d_in[17], *eps1 = (const float*)d_in[18];
  const float* W11 = (const float*)d_in[19], *b11 = (const float*)d_in[20];
  const float* W21 = (const float*)d_in[21], *b21 = (const float*)d_in[22];
  const float* lw2 = (const float*)d_in[23], *lb2 = (const float*)d_in[24], *eps2 = (const float*)d_in[25];
  const float* W12 = (const float*)d_in[26], *b12 = (const float*)d_in[27];
  const float* W22 = (const float*)d_in[28], *b22 = (const float*)d_in[29];
  const float* mW1 = (const float*)d_in[30], *mb1 = (const float*)d_in[31];
  const float* mW2 = (const float*)d_in[32], *mb2 = (const float*)d_in[33];
  float* out = (float*)d_out;

  // ---- workspace layout (same footprint as R8) ----
  char* ws = (char*)d_ws;
  size_t off = 0;
  const size_t NB256 = (size_t)NN*256*2;
  ushort* bufH    = (ushort*)(ws + off); off += NB256;   // h ping buffer
  char*   region  = ws + off;            off += NB256;   // h0 / h pong buffer / catb+hidb
  ushort* h0      = (ushort*)region;
  ushort* hPong   = (ushort*)region;
  ushort* catb    = (ushort*)region;
  ushort* hidb    = (ushort*)(region + (size_t)GG*384*2);
  ushort* wb10 = (ushort*)(ws + off); off += (size_t)256*64*2;
  ushort* wb20 = (ushort*)(ws + off); off += (size_t)65536*2;
  ushort* wb11 = (ushort*)(ws + off); off += (size_t)65536*2;
  ushort* wb21 = (ushort*)(ws + off); off += (size_t)65536*2;
  ushort* wb12 = (ushort*)(ws + off); off += (size_t)65536*2;
  ushort* wb22 = (ushort*)(ws + off); off += (size_t)65536*2;
  ushort* mW1b = (ushort*)(ws + off); off += (size_t)256*384*2;
  ushort* mW2b = (ushort*)(ws + off); off += (size_t)512*256*2;
  float*  eb   = (float*)(ws + off);  off += (size_t)3*4*256*4;
  int* D    = (int*)(ws + off); off += (size_t)NN*4;
  int* bsum = (int*)(ws + off); off += (size_t)NBLK*4;
  int* csr  = (int*)(ws + off); off += (size_t)EE*4;
  size_t needFast = off;

  if (ws_size < needFast) return;

  prep_k<<<2252, 256, 0, stream>>>(W10, W20, W11, W21, W12, W22,
                                   lw0, lb0, lw1, lb1, lw2, lb2, eE, mW1, mW2,
                                   wb10, wb20, wb11, wb21, wb12, wb22, mW1b, mW2b, eb);
  build_h0_k<<<50000, 256, 0, stream>>>(x, opE, h0);

  // ---- CSR build (by dst) ----
  hipMemsetAsync(D, 0, (size_t)NN*4, stream);
  deg_k<<<3125, 256, 0, stream>>>(dst, D);
  scan1_k<<<NBLK, 256, 0, stream>>>(D, bsum);
  scan2_k<<<1, 256, 0, stream>>>(bsum);
  scan3_k<<<NBLK, 256, 0, stream>>>(D, bsum);
  fill_k<<<3125, 256, 0, stream>>>(src, dst, eattr, D, csr); // D -> row ENDS

  // ---- fused layers (gather inside), ping-pong h ----
  layerf_k<64,0><<<6250, 256, 0, stream>>>(h0,    D, csr, eb,        wb10, b10, wb20, b20, eps0, bufH);
  layerf_k<256,1><<<6250, 256, 0, stream>>>(bufH, D, csr, eb + 1024, wb11, b11, wb21, b21, eps1, hPong);
  layerf_k<256,1><<<6250, 256, 0, stream>>>(hPong,D, csr, eb + 2048, wb12, b12, wb22, b22, eps2, bufH);

  // ---- readout + MFMA head ----
  readout_k<<<GG, 256, 0, stream>>>(bufH, batch, x, sqlIds, sqlMask, tok, catb);
  head1_k<<<32, 256, 0, stream>>>(catb, mW1b, mb1, hidb);
  head2_k<<<dim3(16, 4), 256, 0, stream>>>(hidb, mW2b, mb2, out);
}

// Round 11
// 835.698 us; speedup vs baseline: 3.5081x; 1.0579x over previous
//
#include <hip/hip_runtime.h>

#define NN 200000
#define EE 800000
#define GG 2048
#define NBLK ((NN + 255) / 256)   // 782

typedef __attribute__((ext_vector_type(8))) short short8;
typedef __attribute__((ext_vector_type(4))) float f32x4;

__device__ __forceinline__ float bf2f(ushort u){
  unsigned x = ((unsigned)u) << 16;
  return __uint_as_float(x);
}
__device__ __forceinline__ ushort f2bf(float f){
  unsigned x = __float_as_uint(f);
  x += 0x7fffu + ((x >> 16) & 1u);
  return (ushort)(x >> 16);
}

// swizzle a 256xK fp32 weight into MFMA B-fragment order (K=256)
__device__ __forceinline__ void swz256(const float* __restrict__ W, ushort* __restrict__ o, int idx){
  int ks = idx >> 13, rem = idx & 8191;
  int j16 = rem >> 9, rem2 = rem & 511;
  int ln = rem2 >> 3, t = rem2 & 7;
  int row = j16*16 + (ln & 15);
  int k = ks*32 + (ln >> 4)*8 + t;
  o[idx] = f2bf(W[(size_t)row*256 + k]);
}

// ---------------- prep: weight conversion/swizzle + edge-bias tables ----------------
__global__ __launch_bounds__(256) void prep_k(
    const float* __restrict__ W10, const float* __restrict__ W20,
    const float* __restrict__ W11, const float* __restrict__ W21,
    const float* __restrict__ W12, const float* __restrict__ W22,
    const float* __restrict__ lw0, const float* __restrict__ lb0,
    const float* __restrict__ lw1, const float* __restrict__ lb1,
    const float* __restrict__ lw2, const float* __restrict__ lb2,
    const float* __restrict__ eE, const float* __restrict__ mW1,
    const float* __restrict__ mW2,
    ushort* __restrict__ wb10, ushort* __restrict__ wb20,
    ushort* __restrict__ wb11, ushort* __restrict__ wb21,
    ushort* __restrict__ wb12, ushort* __restrict__ wb22,
    ushort* __restrict__ mW1b, ushort* __restrict__ mW2b,
    float* __restrict__ eb)
{
  int b = blockIdx.x, tid = threadIdx.x;
  if (b < 64){ // W1_0 (256x44) -> B-frag swizzled 256x64 (2 kslices), zero-padded
    int idx = b*256 + tid;
    int ks = idx >> 13, rem = idx & 8191;
    int j16 = rem >> 9, rem2 = rem & 511;
    int ln = rem2 >> 3, t = rem2 & 7;
    int row = j16*16 + (ln & 15);
    int k = ks*32 + (ln >> 4)*8 + t;
    wb10[idx] = (k < 44) ? f2bf(W10[row*44 + k]) : (ushort)0;
    return;
  }
  b -= 64;
  if (b < 256){ swz256(W20, wb20, b*256+tid); return; } b -= 256;
  if (b < 256){ swz256(W11, wb11, b*256+tid); return; } b -= 256;
  if (b < 256){ swz256(W21, wb21, b*256+tid); return; } b -= 256;
  if (b < 256){ swz256(W12, wb12, b*256+tid); return; } b -= 256;
  if (b < 256){ swz256(W22, wb22, b*256+tid); return; } b -= 256;
  if (b < 384){ // mW1 (256x323) -> padded row-major (256x384)
    int idx = b*256 + tid; int o = idx / 384, k = idx - o*384;
    mW1b[idx] = (k < 323) ? f2bf(mW1[(size_t)o*323 + k]) : (ushort)0;
    return;
  }
  b -= 384;
  if (b < 512){ int idx = b*256+tid; mW2b[idx] = f2bf(mW2[idx]); return; } b -= 512;
  int li = b >> 2, t = b & 3;
  const float* lw = (li == 0) ? lw0 : ((li == 1) ? lw1 : lw2);
  const float* lb = (li == 0) ? lb0 : ((li == 1) ? lb1 : lb2);
  int d = (li == 0) ? 44 : 256;
  float v = 0.f;
  if (tid < d){
    float a = 0.f;
    #pragma unroll
    for (int j = 0; j < 16; j++) a += eE[t*16 + j] * lw[tid*16 + j];
    v = a + lb[tid];
  }
  eb[(li*4 + t)*256 + tid] = v;
}

// ---------------- h0 = [op_embed[op], nums, 0-pad] as bf16 N x 64 ----------------
__global__ __launch_bounds__(256) void build_h0_k(
    const float* __restrict__ x, const float* __restrict__ opE, ushort* __restrict__ h0)
{
  int idx = blockIdx.x*256 + threadIdx.x;
  int i = idx >> 6, c = idx & 63;
  float v = 0.f;
  if (c < 32){
    int op = (int)x[(size_t)i*13];
    op = op < 0 ? 0 : (op > 63 ? 63 : op);
    v = opE[op*32 + c];
  } else if (c < 44){
    v = x[(size_t)i*13 + (c - 31)];
  }
  h0[idx] = f2bf(v);
}

// ================= CSR build =================
__global__ __launch_bounds__(256) void deg_k(const int* __restrict__ dst, int* __restrict__ D){
  int e = blockIdx.x*256 + threadIdx.x;
  atomicAdd(&D[dst[e]], 1);
}
__global__ __launch_bounds__(256) void scan1_k(int* __restrict__ D, int* __restrict__ bsum){
  __shared__ int s[256];
  int b = blockIdx.x, t = threadIdx.x, idx = b*256 + t;
  int v = (idx < NN) ? D[idx] : 0;
  s[t] = v; __syncthreads();
  for (int off = 1; off < 256; off <<= 1){
    int u = (t >= off) ? s[t-off] : 0;
    __syncthreads();
    s[t] += u;
    __syncthreads();
  }
  if (idx < NN) D[idx] = s[t] - v;
  if (t == 255) bsum[b] = s[255];
}
__global__ __launch_bounds__(256) void scan2_k(int* __restrict__ bsum){
  __shared__ int s[256];
  __shared__ int carry;
  int t = threadIdx.x;
  if (t == 0) carry = 0;
  __syncthreads();
  for (int c0 = 0; c0 < NBLK; c0 += 256){
    int idx = c0 + t;
    int v = (idx < NBLK) ? bsum[idx] : 0;
    s[t] = v; __syncthreads();
    for (int off = 1; off < 256; off <<= 1){
      int u = (t >= off) ? s[t-off] : 0;
      __syncthreads();
      s[t] += u;
      __syncthreads();
    }
    int ex = s[t] - v + carry;
    if (idx < NBLK) bsum[idx] = ex;
    int tot = s[255];
    __syncthreads();
    if (t == 0) carry += tot;
    __syncthreads();
  }
}
__global__ __launch_bounds__(256) void scan3_k(int* __restrict__ D, const int* __restrict__ bsum){
  int b = blockIdx.x, idx = b*256 + threadIdx.x;
  if (idx < NN) D[idx] += bsum[b];
}
__global__ __launch_bounds__(256) void fill_k(const int* __restrict__ src, const int* __restrict__ dst,
                                              const int* __restrict__ et, int* __restrict__ D,
                                              int* __restrict__ csr){
  int e = blockIdx.x*256 + threadIdx.x;
  int d = dst[e];
  int t = et[e]; t = t < 3 ? t : 3;
  int pos = atomicAdd(&D[d], 1);
  csr[pos] = src[e] | (t << 18);
}

// ---------------- fused layer: gather + z + GEMM1 + GEMM2 + LN + resid + leaky ----------------
// 32 rows/block, grid 6250. Phase A: quad-row edge streams, float4 eb reads, 32-bit
// byte-offset addressing. Residual re-reads global h (L2/L3-hot) — NO HT tile.
template<int KD, int RESID>
__global__ __launch_bounds__(256) void layerf_k(
    const ushort* __restrict__ hsrc, const int* __restrict__ Dend, const int* __restrict__ csr,
    const float* __restrict__ ebL,
    const ushort* __restrict__ W1s, const float* __restrict__ b1,
    const ushort* __restrict__ W2s, const float* __restrict__ b2,
    const float* __restrict__ epsp, ushort* __restrict__ hout)
{
  __shared__ ushort ZT[32][264];
  __shared__ float ebs[1024];
  __shared__ float red1[32][4], red2[32][4], mnL[32], rsL[32];
  const int tid = threadIdx.x, lane = tid & 63, wv = tid >> 6;
  const int l15 = lane & 15, lq = lane >> 4;
  const int rowBase = blockIdx.x * 32;
  const float epv = 1.0f + epsp[0];
  const char* hb = (const char*)hsrc;

  if (KD == 256){
    for (int i = tid; i < 1024; i += 256) ebs[i] = ebL[i];
  } else {
    if (tid < 256) ebs[tid] = ebL[(tid >> 6)*256 + (tid & 63)];  // compact [4][64]
  }
  __syncthreads();

  // ---- A: z = (1+eps)h[r] + sum_e relu(h[src]+eb[et]) -> ZT ----
  if (KD == 256){
    const int c = lane * 4;         // element col
    const unsigned c2 = lane * 8;   // byte offset within row
    #pragma unroll 1
    for (int it = 0; it < 2; it++){
      int rr0 = wv*8 + it*4;
      int r0 = rowBase + rr0;
      float4 A0, A1, A2, A3;
      {
        ushort4 q0 = *(const ushort4*)(hb + (size_t)(r0+0)*512 + c2);
        ushort4 q1 = *(const ushort4*)(hb + (size_t)(r0+1)*512 + c2);
        ushort4 q2 = *(const ushort4*)(hb + (size_t)(r0+2)*512 + c2);
        ushort4 q3 = *(const ushort4*)(hb + (size_t)(r0+3)*512 + c2);
        A0 = make_float4(epv*bf2f(q0.x), epv*bf2f(q0.y), epv*bf2f(q0.z), epv*bf2f(q0.w));
        A1 = make_float4(epv*bf2f(q1.x), epv*bf2f(q1.y), epv*bf2f(q1.z), epv*bf2f(q1.w));
        A2 = make_float4(epv*bf2f(q2.x), epv*bf2f(q2.y), epv*bf2f(q2.z), epv*bf2f(q2.w));
        A3 = make_float4(epv*bf2f(q3.x), epv*bf2f(q3.y), epv*bf2f(q3.z), epv*bf2f(q3.w));
      }
      int bm1 = (r0 == 0) ? 0 : Dend[r0-1];
      int e0 = Dend[r0], e1 = Dend[r0+1], e2 = Dend[r0+2], e3 = Dend[r0+3];
      int st0 = bm1, st1 = e0, st2 = e1, st3 = e2;
      int n0 = e0 - st0, n1 = e1 - st1, n2 = e2 - st2, n3 = e3 - st3;
      int nmax = n0 > n1 ? n0 : n1;
      nmax = nmax > n2 ? nmax : n2;
      nmax = nmax > n3 ? nmax : n3;
      ushort4 z4; z4.x = z4.y = z4.z = z4.w = 0;
      ushort4 sv0 = z4, sv1 = z4, sv2 = z4, sv3 = z4;
      int t0 = 0, t1 = 0, t2 = 0, t3 = 0;
      if (n0 > 0){ int p = csr[st0]; sv0 = *(const ushort4*)(hb + (unsigned)((p & 0x3FFFF) << 9) + c2); t0 = ((p >> 18) & 3)*256; }
      if (n1 > 0){ int p = csr[st1]; sv1 = *(const ushort4*)(hb + (unsigned)((p & 0x3FFFF) << 9) + c2); t1 = ((p >> 18) & 3)*256; }
      if (n2 > 0){ int p = csr[st2]; sv2 = *(const ushort4*)(hb + (unsigned)((p & 0x3FFFF) << 9) + c2); t2 = ((p >> 18) & 3)*256; }
      if (n3 > 0){ int p = csr[st3]; sv3 = *(const ushort4*)(hb + (unsigned)((p & 0x3FFFF) << 9) + c2); t3 = ((p >> 18) & 3)*256; }
      for (int k = 0; k < nmax; k++){
        ushort4 c0 = sv0, c1 = sv1, c2v = sv2, c3 = sv3;
        int u0 = t0, u1 = t1, u2 = t2, u3 = t3;
        if (k+1 < n0){ int p = csr[st0+k+1]; sv0 = *(const ushort4*)(hb + (unsigned)((p & 0x3FFFF) << 9) + c2); t0 = ((p >> 18) & 3)*256; }
        if (k+1 < n1){ int p = csr[st1+k+1]; sv1 = *(const ushort4*)(hb + (unsigned)((p & 0x3FFFF) << 9) + c2); t1 = ((p >> 18) & 3)*256; }
        if (k+1 < n2){ int p = csr[st2+k+1]; sv2 = *(const ushort4*)(hb + (unsigned)((p & 0x3FFFF) << 9) + c2); t2 = ((p >> 18) & 3)*256; }
        if (k+1 < n3){ int p = csr[st3+k+1]; sv3 = *(const ushort4*)(hb + (unsigned)((p & 0x3FFFF) << 9) + c2); t3 = ((p >> 18) & 3)*256; }
        if (k < n0){
          const float4 ev = *(const float4*)&ebs[u0 + c];
          float v;
          v = bf2f(c0.x) + ev.x; A0.x += v > 0.f ? v : 0.f;
          v = bf2f(c0.y) + ev.y; A0.y += v > 0.f ? v : 0.f;
          v = bf2f(c0.z) + ev.z; A0.z += v > 0.f ? v : 0.f;
          v = bf2f(c0.w) + ev.w; A0.w += v > 0.f ? v : 0.f;
        }
        if (k < n1){
          const float4 ev = *(const float4*)&ebs[u1 + c];
          float v;
          v = bf2f(c1.x) + ev.x; A1.x += v > 0.f ? v : 0.f;
          v = bf2f(c1.y) + ev.y; A1.y += v > 0.f ? v : 0.f;
          v = bf2f(c1.z) + ev.z; A1.z += v > 0.f ? v : 0.f;
          v = bf2f(c1.w) + ev.w; A1.w += v > 0.f ? v : 0.f;
        }
        if (k < n2){
          const float4 ev = *(const float4*)&ebs[u2 + c];
          float v;
          v = bf2f(c2v.x) + ev.x; A2.x += v > 0.f ? v : 0.f;
          v = bf2f(c2v.y) + ev.y; A2.y += v > 0.f ? v : 0.f;
          v = bf2f(c2v.z) + ev.z; A2.z += v > 0.f ? v : 0.f;
          v = bf2f(c2v.w) + ev.w; A2.w += v > 0.f ? v : 0.f;
        }
        if (k < n3){
          const float4 ev = *(const float4*)&ebs[u3 + c];
          float v;
          v = bf2f(c3.x) + ev.x; A3.x += v > 0.f ? v : 0.f;
          v = bf2f(c3.y) + ev.y; A3.y += v > 0.f ? v : 0.f;
          v = bf2f(c3.z) + ev.z; A3.z += v > 0.f ? v : 0.f;
          v = bf2f(c3.w) + ev.w; A3.w += v > 0.f ? v : 0.f;
        }
      }
      ushort4 o;
      o.x = f2bf(A0.x); o.y = f2bf(A0.y); o.z = f2bf(A0.z); o.w = f2bf(A0.w);
      *(ushort4*)&ZT[rr0+0][c] = o;
      o.x = f2bf(A1.x); o.y = f2bf(A1.y); o.z = f2bf(A1.z); o.w = f2bf(A1.w);
      *(ushort4*)&ZT[rr0+1][c] = o;
      o.x = f2bf(A2.x); o.y = f2bf(A2.y); o.z = f2bf(A2.z); o.w = f2bf(A2.w);
      *(ushort4*)&ZT[rr0+2][c] = o;
      o.x = f2bf(A3.x); o.y = f2bf(A3.y); o.z = f2bf(A3.z); o.w = f2bf(A3.w);
      *(ushort4*)&ZT[rr0+3][c] = o;
    }
  } else {
    const int c = l15 * 4;
    const unsigned c2 = l15 * 8;
    #pragma unroll 1
    for (int it = 0; it < 2; it++){
      int rr = wv*8 + it*4 + lq;
      int r = rowBase + rr;
      const ushort4 hv = *(const ushort4*)(hb + (size_t)r*128 + c2);
      float a0 = epv*bf2f(hv.x), a1 = epv*bf2f(hv.y), a2 = epv*bf2f(hv.z), a3 = epv*bf2f(hv.w);
      int st = (r == 0) ? 0 : Dend[r-1];
      int en = Dend[r];
      if (st < en){
        int p = csr[st];
        ushort4 sv = *(const ushort4*)(hb + (unsigned)((p & 0x3FFFF) << 7) + c2);
        int tt = ((p >> 18) & 3)*64;
        for (int e = st; e < en; e++){
          ushort4 cur = sv; int tc = tt;
          int e2 = (e+1 < en) ? e+1 : e;
          int p2 = csr[e2];
          sv = *(const ushort4*)(hb + (unsigned)((p2 & 0x3FFFF) << 7) + c2);
          tt = ((p2 >> 18) & 3)*64;
          const float4 ev = *(const float4*)&ebs[tc + c];
          float v;
          v = bf2f(cur.x) + ev.x; a0 += v > 0.f ? v : 0.f;
          v = bf2f(cur.y) + ev.y; a1 += v > 0.f ? v : 0.f;
          v = bf2f(cur.z) + ev.z; a2 += v > 0.f ? v : 0.f;
          v = bf2f(cur.w) + ev.w; a3 += v > 0.f ? v : 0.f;
        }
      }
      ushort4 o; o.x=f2bf(a0); o.y=f2bf(a1); o.z=f2bf(a2); o.w=f2bf(a3);
      *(ushort4*)&ZT[rr][c] = o;
    }
  }
  __syncthreads();

  // ---- B: t = relu(z @ W1^T + b1), wave tile 32x64 ----
  f32x4 acc[2][4];
  #pragma unroll
  for (int i = 0; i < 2; i++)
    #pragma unroll
    for (int j = 0; j < 4; j++){ f32x4 z = {0.f,0.f,0.f,0.f}; acc[i][j] = z; }

  #pragma unroll
  for (int s = 0; s < KD/32; s++){
    short8 af[2], bfv[4];
    #pragma unroll
    for (int j = 0; j < 4; j++)
      bfv[j] = *(const short8*)(W1s + ((size_t)(s*16 + wv*4 + j)*64 + lane)*8);
    #pragma unroll
    for (int i = 0; i < 2; i++)
      af[i] = *(const short8*)&ZT[i*16 + l15][s*32 + lq*8];
    #pragma unroll
    for (int i = 0; i < 2; i++)
      #pragma unroll
      for (int j = 0; j < 4; j++)
        acc[i][j] = __builtin_amdgcn_mfma_f32_16x16x32_bf16(af[i], bfv[j], acc[i][j], 0, 0, 0);
  }
  __syncthreads();

  // ---- C: t -> ZT ----
  {
    float b1c[4];
    #pragma unroll
    for (int j = 0; j < 4; j++) b1c[j] = b1[wv*64 + j*16 + l15];
    #pragma unroll
    for (int i = 0; i < 2; i++)
      #pragma unroll
      for (int j = 0; j < 4; j++){
        int cc = wv*64 + j*16 + l15;
        #pragma unroll
        for (int rg = 0; rg < 4; rg++){
          int r = i*16 + (lq << 2) + rg;
          float v = acc[i][j][rg] + b1c[j];
          v = v > 0.f ? v : 0.f;
          ZT[r][cc] = f2bf(v);
        }
      }
  }
  __syncthreads();

  // ---- D: y = t @ W2^T ----
  #pragma unroll
  for (int i = 0; i < 2; i++)
    #pragma unroll
    for (int j = 0; j < 4; j++){ f32x4 z = {0.f,0.f,0.f,0.f}; acc[i][j] = z; }

  #pragma unroll
  for (int s = 0; s < 8; s++){
    short8 af[2], bfv[4];
    #pragma unroll
    for (int j = 0; j < 4; j++)
      bfv[j] = *(const short8*)(W2s + ((size_t)(s*16 + wv*4 + j)*64 + lane)*8);
    #pragma unroll
    for (int i = 0; i < 2; i++)
      af[i] = *(const short8*)&ZT[i*16 + l15][s*32 + lq*8];
    #pragma unroll
    for (int i = 0; i < 2; i++)
      #pragma unroll
      for (int j = 0; j < 4; j++)
        acc[i][j] = __builtin_amdgcn_mfma_f32_16x16x32_bf16(af[i], bfv[j], acc[i][j], 0, 0, 0);
  }

  // ---- E: LayerNorm stats ----
  float b2c[4];
  #pragma unroll
  for (int j = 0; j < 4; j++) b2c[j] = b2[wv*64 + j*16 + l15];
  #pragma unroll
  for (int i = 0; i < 2; i++){
    #pragma unroll
    for (int rg = 0; rg < 4; rg++){
      float s1 = 0.f, s2 = 0.f;
      #pragma unroll
      for (int j = 0; j < 4; j++){
        float y = acc[i][j][rg] + b2c[j];
        s1 += y; s2 += y*y;
      }
      #pragma unroll
      for (int m = 1; m < 16; m <<= 1){
        s1 += __shfl_xor(s1, m, 64);
        s2 += __shfl_xor(s2, m, 64);
      }
      if (l15 == 0){
        int r = i*16 + (lq << 2) + rg;
        red1[r][wv] = s1; red2[r][wv] = s2;
      }
    }
  }
  __syncthreads();
  if (tid < 32){
    float s1 = red1[tid][0] + red1[tid][1] + red1[tid][2] + red1[tid][3];
    float s2 = red2[tid][0] + red2[tid][1] + red2[tid][2] + red2[tid][3];
    float mn = s1 * (1.f/256.f);
    float vr = s2 * (1.f/256.f) - mn*mn;
    mnL[tid] = mn;
    rsL[tid] = rsqrtf(vr + 1e-5f);
  }
  __syncthreads();
  // ---- F: LN + resid (global re-read, L2/L3-hot) + leaky -> ZT ----
  #pragma unroll
  for (int i = 0; i < 2; i++){
    #pragma unroll
    for (int rg = 0; rg < 4; rg++){
      int r = i*16 + (lq << 2) + rg;
      float mn = mnL[r], rs = rsL[r];
      #pragma unroll
      for (int j = 0; j < 4; j++){
        int cc = wv*64 + j*16 + l15;
        float y = acc[i][j][rg] + b2c[j];
        float v = (y - mn) * rs;
        if (RESID) v += bf2f(hsrc[(size_t)(rowBase + r)*256 + cc]);
        v = v > 0.f ? v : 0.1f*v;
        ZT[r][cc] = f2bf(v);
      }
    }
  }
  __syncthreads();
  // ---- G: coalesced store ----
  #pragma unroll
  for (int p = 0; p < 8; p++){
    int r = p*4 + (tid >> 6);
    int c = (tid & 63) * 4;
    *(ushort4*)(hout + (size_t)(rowBase + r)*256 + c) = *(const ushort4*)&ZT[r][c];
  }
}

// ---------------- readout -> catb bf16 (G x 384); row-parallel waves ----------------
__global__ __launch_bounds__(256) void readout_k(
    const ushort* __restrict__ h, const int* __restrict__ batch, const float* __restrict__ x,
    const int* __restrict__ sqlIds, const float* __restrict__ sqlMask,
    const float* __restrict__ tok, ushort* __restrict__ catb)
{
  int g = blockIdx.x, tid = threadIdx.x;
  const int lane = tid & 63, wv = tid >> 6;
  __shared__ int se[2];
  __shared__ float part[4][256];
  __shared__ float tpart[4][64];
  __shared__ float mpart[4];
  __shared__ float xs[2];
  if (tid < 2){
    int target = g + tid;
    int lo = 0, hi = NN;
    while (lo < hi){ int mid = (lo + hi) >> 1; if (batch[mid] < target) lo = mid + 1; else hi = mid; }
    se[tid] = lo;
  }
  __syncthreads();
  int start = se[0], end = se[1];
  // graph sum: wave wv takes rows start+wv, step 4; lane covers 4 cols
  {
    float a0 = 0.f, a1 = 0.f, a2 = 0.f, a3 = 0.f;
    for (int i = start + wv; i < end; i += 4){
      ushort4 q = *(const ushort4*)(h + (size_t)i*256 + lane*4);
      a0 += bf2f(q.x); a1 += bf2f(q.y); a2 += bf2f(q.z); a3 += bf2f(q.w);
    }
    part[wv][lane*4 + 0] = a0;
    part[wv][lane*4 + 1] = a1;
    part[wv][lane*4 + 2] = a2;
    part[wv][lane*4 + 3] = a3;
  }
  // stats: wave 2 -> col5 (fanout), wave 3 -> col4 (cost), wave-parallel + shuffle reduce
  if (wv >= 2){
    int col = (wv == 2) ? 5 : 4;
    float s = 0.f;
    for (int i = start + lane; i < end; i += 64) s += x[(size_t)i*13 + col];
    #pragma unroll
    for (int m = 1; m < 64; m <<= 1) s += __shfl_xor(s, m, 64);
    if (lane == 0) xs[wv - 2] = s;
  }
  // text pooling
  {
    int c = lane;
    float acc = 0.f, m = 0.f;
    for (int s = wv; s < 128; s += 4){
      int id = sqlIds[g*128 + s];
      float mk = sqlMask[g*128 + s];
      m += mk;
      acc += tok[(size_t)id*64 + c] * mk;
    }
    tpart[wv][c] = acc;
    if (c == 0) mpart[wv] = m;
  }
  __syncthreads();
  // combine graph sum
  {
    float gsum = part[0][tid] + part[1][tid] + part[2][tid] + part[3][tid];
    catb[(size_t)g*384 + tid] = f2bf(gsum);
  }
  if (tid == 0){
    float cnt = (float)(end - start);
    float dn = cnt > 1.f ? cnt : 1.f;
    catb[(size_t)g*384 + 256] = f2bf(cnt);
    catb[(size_t)g*384 + 257] = f2bf(xs[0] / dn);
    catb[(size_t)g*384 + 258] = f2bf(xs[1] / dn);
  }
  if (tid < 64){
    float L = mpart[0] + mpart[1] + mpart[2] + mpart[3];
    L = L > 1.f ? L : 1.f;
    float tsum = tpart[0][tid] + tpart[1][tid] + tpart[2][tid] + tpart[3][tid];
    catb[(size_t)g*384 + 259 + tid] = f2bf(tsum / L);
  }
  if (tid >= 64 && tid < 125){
    catb[(size_t)g*384 + 259 + tid] = 0;   // zero pad 323..383
  }
}

// ---------------- head GEMM1: hid = leaky(catb @ mW1b^T + mb1), bf16 out ----------------
__global__ __launch_bounds__(256) void head1_k(
    const ushort* __restrict__ catb, const ushort* __restrict__ W1b,
    const float* __restrict__ b1, ushort* __restrict__ hidb)
{
  __shared__ ushort smem[64*72 + 256*72];
  ushort (*As)[72] = (ushort(*)[72])smem;
  ushort (*Ws)[72] = (ushort(*)[72])(smem + 64*72);
  const int tid = threadIdx.x, lane = tid & 63, wv = tid >> 6;
  const int rowBase = blockIdx.x * 64;
  f32x4 acc[4][4];
  #pragma unroll
  for (int i = 0; i < 4; i++)
    #pragma unroll
    for (int j = 0; j < 4; j++){ f32x4 z = {0.f,0.f,0.f,0.f}; acc[i][j] = z; }

  for (int k0 = 0; k0 < 384; k0 += 64){
    __syncthreads();
    #pragma unroll
    for (int p = 0; p < 4; p++){
      int r = p*16 + (tid >> 4);
      int kk = (tid & 15) * 4;
      *(ushort4*)&As[r][kk] = *(const ushort4*)(catb + (size_t)(rowBase + r)*384 + k0 + kk);
    }
    #pragma unroll
    for (int p = 0; p < 16; p++){
      int oc = p*16 + (tid >> 4);
      int kk = (tid & 15) * 4;
      *(ushort4*)&Ws[oc][kk] = *(const ushort4*)(W1b + (size_t)oc*384 + k0 + kk);
    }
    __syncthreads();
    #pragma unroll
    for (int kc = 0; kc < 2; kc++){
      short8 af[4], bfv[4];
      #pragma unroll
      for (int i = 0; i < 4; i++)
        af[i] = *(const short8*)&As[i*16 + (lane & 15)][kc*32 + (lane >> 4)*8];
      #pragma unroll
      for (int j = 0; j < 4; j++)
        bfv[j] = *(const short8*)&Ws[wv*64 + j*16 + (lane & 15)][kc*32 + (lane >> 4)*8];
      #pragma unroll
      for (int i = 0; i < 4; i++)
        #pragma unroll
        for (int j = 0; j < 4; j++)
          acc[i][j] = __builtin_amdgcn_mfma_f32_16x16x32_bf16(af[i], bfv[j], acc[i][j], 0, 0, 0);
    }
  }
  __syncthreads();
  ushort (*Cs)[264] = (ushort(*)[264])smem;
  #pragma unroll
  for (int j = 0; j < 4; j++){
    int cc = wv*64 + j*16 + (lane & 15);
    float bb = b1[cc];
    #pragma unroll
    for (int i = 0; i < 4; i++){
      #pragma unroll
      for (int rg = 0; rg < 4; rg++){
        int r = i*16 + ((lane >> 4) << 2) + rg;
        float v = acc[i][j][rg] + bb;
        v = v > 0.f ? v : 0.1f*v;
        Cs[r][cc] = f2bf(v);
      }
    }
  }
  __syncthreads();
  #pragma unroll
  for (int p = 0; p < 16; p++){
    int r = p*4 + (tid >> 6);
    int c = (tid & 63) * 4;
    *(ushort4*)(hidb + (size_t)(rowBase + r)*256 + c) = *(const ushort4*)&Cs[r][c];
  }
}

// ---------------- head GEMM2: out = hidb @ mW2b^T + mb2, fp32 out ----------------
__global__ __launch_bounds__(256) void head2_k(
    const ushort* __restrict__ hidb, const ushort* __restrict__ W2b,
    const float* __restrict__ b2, float* __restrict__ out)
{
  __shared__ float smemf[128*132];
  ushort (*As)[72] = (ushort(*)[72])smemf;
  ushort (*Bs)[72] = (ushort(*)[72])((ushort*)smemf + 128*72);
  const int tid = threadIdx.x, lane = tid & 63, wv = tid >> 6;
  const int wr = (wv >> 1) * 64;
  const int wc = (wv & 1) * 64;
  const int rowBase = blockIdx.x * 128;
  const int colBase = blockIdx.y * 128;
  const int lr = tid >> 4, lk = (tid & 15) * 4;

  f32x4 acc[4][4];
  #pragma unroll
  for (int i = 0; i < 4; i++)
    #pragma unroll
    for (int j = 0; j < 4; j++){ f32x4 z = {0.f,0.f,0.f,0.f}; acc[i][j] = z; }

  for (int k0 = 0; k0 < 256; k0 += 64){
    __syncthreads();
    #pragma unroll
    for (int p = 0; p < 8; p++){
      int r = lr + p*16;
      *(ushort4*)&As[r][lk] = *(const ushort4*)(hidb + (size_t)(rowBase + r)*256 + k0 + lk);
      *(ushort4*)&Bs[r][lk] = *(const ushort4*)(W2b + (size_t)(colBase + r)*256 + k0 + lk);
    }
    __syncthreads();
    #pragma unroll
    for (int kc = 0; kc < 2; kc++){
      short8 af[4], bfv[4];
      #pragma unroll
      for (int i = 0; i < 4; i++)
        af[i] = *(const short8*)&As[wr + i*16 + (lane & 15)][kc*32 + (lane >> 4)*8];
      #pragma unroll
      for (int j = 0; j < 4; j++)
        bfv[j] = *(const short8*)&Bs[wc + j*16 + (lane & 15)][kc*32 + (lane >> 4)*8];
      #pragma unroll
      for (int i = 0; i < 4; i++)
        #pragma unroll
        for (int j = 0; j < 4; j++)
          acc[i][j] = __builtin_amdgcn_mfma_f32_16x16x32_bf16(af[i], bfv[j], acc[i][j], 0, 0, 0);
    }
  }
  __syncthreads();
  float (*Cs)[132] = (float(*)[132])smemf;
  #pragma unroll
  for (int j = 0; j < 4; j++){
    int cl = wc + j*16 + (lane & 15);
    float bb = b2[colBase + cl];
    #pragma unroll
    for (int i = 0; i < 4; i++){
      int r0 = wr + i*16 + ((lane >> 4) << 2);
      #pragma unroll
      for (int rg = 0; rg < 4; rg++)
        Cs[r0 + rg][cl] = acc[i][j][rg] + bb;
    }
  }
  __syncthreads();
  #pragma unroll
  for (int p = 0; p < 16; p++){
    int r = (tid >> 5) + p*8;
    int c4 = (tid & 31) * 4;
    *(float4*)(out + (size_t)(rowBase + r)*512 + colBase + c4) = *(const float4*)&Cs[r][c4];
  }
}

extern "C" void kernel_launch(void* const* d_in, const int* in_sizes, int n_in,
                              void* d_out, int out_size, void* d_ws, size_t ws_size,
                              hipStream_t stream)
{
  const float* x       = (const float*)d_in[0];
  const int*   ei      = (const int*)d_in[1];
  const int*   src     = ei;
  const int*   dst     = ei + EE;
  const int*   eattr   = (const int*)d_in[2];
  const int*   batch   = (const int*)d_in[3];
  const int*   sqlIds  = (const int*)d_in[4];
  const float* sqlMask = (const float*)d_in[5];
  const float* opE     = (const float*)d_in[6];
  const float* eE      = (const float*)d_in[7];
  const float* tok     = (const float*)d_in[8];
  const float* lw0 = (const float*)d_in[9],  *lb0 = (const float*)d_in[10], *eps0 = (const float*)d_in[11];
  const float* W10 = (const float*)d_in[12], *b10 = (const float*)d_in[13];
  const float* W20 = (const float*)d_in[14], *b20 = (const float*)d_in[15];
  const float* lw1 = (const float*)d_in[16], *lb1 = (const float*)d_in[17], *eps1 = (const float*)d_in[18];
  const float* W11 = (const float*)d_in[19], *b11 = (const float*)d_in[20];
  const float* W21 = (const float*)d_in[21], *b21 = (const float*)d_in[22];
  const float* lw2 = (const float*)d_in[23], *lb2 = (const float*)d_in[24], *eps2 = (const float*)d_in[25];
  const float* W12 = (const float*)d_in[26], *b12 = (const float*)d_in[27];
  const float* W22 = (const float*)d_in[28], *b22 = (const float*)d_in[29];
  const float* mW1 = (const float*)d_in[30], *mb1 = (const float*)d_in[31];
  const float* mW2 = (const float*)d_in[32], *mb2 = (const float*)d_in[33];
  float* out = (float*)d_out;

  // ---- workspace layout (same footprint as R10) ----
  char* ws = (char*)d_ws;
  size_t off = 0;
  const size_t NB256 = (size_t)NN*256*2;
  ushort* bufH    = (ushort*)(ws + off); off += NB256;   // h ping buffer
  char*   region  = ws + off;            off += NB256;   // h0 / h pong buffer / catb+hidb
  ushort* h0      = (ushort*)region;
  ushort* hPong   = (ushort*)region;
  ushort* catb    = (ushort*)region;
  ushort* hidb    = (ushort*)(region + (size_t)GG*384*2);
  ushort* wb10 = (ushort*)(ws + off); off += (size_t)256*64*2;
  ushort* wb20 = (ushort*)(ws + off); off += (size_t)65536*2;
  ushort* wb11 = (ushort*)(ws + off); off += (size_t)65536*2;
  ushort* wb21 = (ushort*)(ws + off); off += (size_t)65536*2;
  ushort* wb12 = (ushort*)(ws + off); off += (size_t)65536*2;
  ushort* wb22 = (ushort*)(ws + off); off += (size_t)65536*2;
  ushort* mW1b = (ushort*)(ws + off); off += (size_t)256*384*2;
  ushort* mW2b = (ushort*)(ws + off); off += (size_t)512*256*2;
  float*  eb   = (float*)(ws + off);  off += (size_t)3*4*256*4;
  int* D    = (int*)(ws + off); off += (size_t)NN*4;
  int* bsum = (int*)(ws + off); off += (size_t)NBLK*4;
  int* csr  = (int*)(ws + off); off += (size_t)EE*4;
  size_t needFast = off;

  if (ws_size < needFast) return;

  prep_k<<<2252, 256, 0, stream>>>(W10, W20, W11, W21, W12, W22,
                                   lw0, lb0, lw1, lb1, lw2, lb2, eE, mW1, mW2,
                                   wb10, wb20, wb11, wb21, wb12, wb22, mW1b, mW2b, eb);
  build_h0_k<<<50000, 256, 0, stream>>>(x, opE, h0);

  // ---- CSR build (by dst) ----
  hipMemsetAsync(D, 0, (size_t)NN*4, stream);
  deg_k<<<3125, 256, 0, stream>>>(dst, D);
  scan1_k<<<NBLK, 256, 0, stream>>>(D, bsum);
  scan2_k<<<1, 256, 0, stream>>>(bsum);
  scan3_k<<<NBLK, 256, 0, stream>>>(D, bsum);
  fill_k<<<3125, 256, 0, stream>>>(src, dst, eattr, D, csr); // D -> row ENDS

  // ---- fused layers (gather inside), ping-pong h ----
  layerf_k<64,0><<<6250, 256, 0, stream>>>(h0,    D, csr, eb,        wb10, b10, wb20, b20, eps0, bufH);
  layerf_k<256,1><<<6250, 256, 0, stream>>>(bufH, D, csr, eb + 1024, wb11, b11, wb21, b21, eps1, hPong);
  layerf_k<256,1><<<6250, 256, 0, stream>>>(hPong,D, csr, eb + 2048, wb12, b12, wb22, b22, eps2, bufH);

  // ---- readout + MFMA head ----
  readout_k<<<GG, 256, 0, stream>>>(bufH, batch, x, sqlIds, sqlMask, tok, catb);
  head1_k<<<32, 256, 0, stream>>>(catb, mW1b, mb1, hidb);
  head2_k<<<dim3(16, 4), 256, 0, stream>>>(hidb, mW2b, mb2, out);
}